// Round 5
// baseline (426.537 us; speedup 1.0000x reference)
//
#include <hip/hip_runtime.h>

// GCN forward: 3x GCNConv (128->64->64->2) + linear head (2->16).
// N=100000 nodes, E=1600000 edges (+self-loops handled analytically).
// Strategy: dst-bucket edges per call (histogram-with-rank + unordered block
// scan + atomic-free scatter), then atomic-free segment-sum gathers.
// dis[] is pre-folded into the transform outputs: T'[v] = dis[v]*t[v], so
// O[i] = dis[i]*(T'[i] + sum_{s in bucket(i)} T'[s]) + b.
// Random-access passes use 8 ops/thread batches: the walls are latency x
// in-flight depth (returning atomics ~900cyc), so MLP-per-wave is the lever.

#define NF 128
#define NH 64
#define CE 8   // edges per thread in k_cnt / k_scatter

// Detect int64 vs int32 edge_index layout + zero the histogram.
__global__ void k_init(const int* __restrict__ ei, int* __restrict__ flag,
                       int* __restrict__ cnt, int* __restrict__ gcount, int n) {
    int i = blockIdx.x * 256 + threadIdx.x;
    if (i < n) cnt[i] = 0;
    if (blockIdx.x == 0 && threadIdx.x == 0) {
        int f = 1;
        #pragma unroll
        for (int k = 1; k < 32; k += 2) if (ei[k] != 0) f = 0;
        *flag = f;   // 1 => int64 (stride 2 in int32 words), 0 => int32
        *gcount = 0;
    }
}

// Histogram dst; atomic return value = edge's within-bucket rank.
// 8 edges/thread: 8 independent returning atomics in flight per lane.
__global__ void __launch_bounds__(256) k_cnt(
        const int* __restrict__ ei, const int* __restrict__ fmt,
        int* __restrict__ cnt, int* __restrict__ rank, int E) {
    int sh = *fmt;
    long long base = (long long)blockIdx.x * (256 * CE) + threadIdx.x;
    int d[CE]; bool v[CE]; int r[CE];
    #pragma unroll
    for (int k = 0; k < CE; ++k) {
        long long e = base + k * 256;
        v[k] = e < E;
        d[k] = v[k] ? ei[(long long)(E + e) << sh] : 0;
    }
    #pragma unroll
    for (int k = 0; k < CE; ++k)
        if (v[k]) r[k] = atomicAdd(&cnt[d[k]], 1);
    #pragma unroll
    for (int k = 0; k < CE; ++k)
        if (v[k]) rank[base + k * 256] = r[k];
}

// Unordered exclusive scan: block-local Hillis-Steele + atomic block base.
// Bucket ranges are a valid disjoint partition regardless of block order.
__global__ void __launch_bounds__(256) k_scan(
        const int* __restrict__ cnt, int* __restrict__ start,
        float* __restrict__ dis, int* __restrict__ gcount, int n) {
    __shared__ int s[256];
    __shared__ int base_s;
    int i = blockIdx.x * 256 + threadIdx.x;
    int c = (i < n) ? cnt[i] : 0;
    s[threadIdx.x] = c;
    __syncthreads();
    for (int off = 1; off < 256; off <<= 1) {
        int v = s[threadIdx.x];
        int u = (threadIdx.x >= off) ? s[threadIdx.x - off] : 0;
        __syncthreads();
        s[threadIdx.x] = v + u;
        __syncthreads();
    }
    if (threadIdx.x == 255) base_s = atomicAdd(gcount, s[255]);
    __syncthreads();
    if (i < n) {
        start[i] = base_s + s[threadIdx.x] - c;
        dis[i] = rsqrtf(1.0f + (float)c);   // degree includes self-loop
    }
}

// Atomic-free scatter: position is start[dst] + precomputed rank.
// 8 edges/thread for gather/store MLP.
__global__ void __launch_bounds__(256) k_scatter(
        const int* __restrict__ ei, const int* __restrict__ fmt,
        const int* __restrict__ start, const int* __restrict__ rank,
        int* __restrict__ esrc, int E) {
    int sh = *fmt;
    long long base = (long long)blockIdx.x * (256 * CE) + threadIdx.x;
    int s[CE], d[CE], rk[CE], st[CE]; bool v[CE];
    #pragma unroll
    for (int k = 0; k < CE; ++k) {
        long long e = base + k * 256;
        v[k] = e < E;
        s[k] = v[k] ? ei[(long long)e << sh] : 0;
        d[k] = v[k] ? ei[(long long)(E + e) << sh] : 0;
        rk[k] = v[k] ? rank[base + k * 256] : 0;
    }
    #pragma unroll
    for (int k = 0; k < CE; ++k)
        if (v[k]) st[k] = start[d[k]];
    #pragma unroll
    for (int k = 0; k < CE; ++k)
        if (v[k]) esrc[st[k] + rk[k]] = s[k];
}

// T[n,NH] = dis[n] * (X[n,K] @ W[K,NH]).
// 64 rows/block, 256 threads, 4 rows x 4 cols per thread (16 acc).
template<int K>
__global__ void __launch_bounds__(256) k_gemm(
        const float* __restrict__ X, const float* __restrict__ W,
        const float* __restrict__ dis, float* __restrict__ T, int n) {
    constexpr int KP = K + 4;
    __shared__ float xs[64 * KP];
    __shared__ float Ws[K * NH];
    for (int i = threadIdx.x; i < K * NH / 4; i += 256)
        ((float4*)Ws)[i] = ((const float4*)W)[i];
    long long rowbase = (long long)blockIdx.x * 64;
    const float4* X4 = (const float4*)(X + rowbase * K);
    long long lim4 = ((long long)n * K - rowbase * K) >> 2;  // remaining float4s
    for (int i = threadIdx.x; i < 16 * K; i += 256) {
        float4 v = (i < lim4) ? X4[i] : make_float4(0.f, 0.f, 0.f, 0.f);
        int r = i / (K / 4), kk = (i % (K / 4)) * 4;
        *(float4*)&xs[r * KP + kk] = v;
    }
    __syncthreads();
    int c0 = (threadIdx.x & 15) * 4;
    int r0 = (threadIdx.x >> 4) * 4;
    const float* x0 = &xs[(r0 + 0) * KP];
    const float* x1 = &xs[(r0 + 1) * KP];
    const float* x2 = &xs[(r0 + 2) * KP];
    const float* x3 = &xs[(r0 + 3) * KP];
    float4 a0{0,0,0,0}, a1{0,0,0,0}, a2{0,0,0,0}, a3{0,0,0,0};
    #pragma unroll 4
    for (int k = 0; k < K; ++k) {
        float4 w = *(const float4*)&Ws[k * NH + c0];
        float v0 = x0[k], v1 = x1[k], v2 = x2[k], v3 = x3[k];
        a0.x += v0 * w.x; a0.y += v0 * w.y; a0.z += v0 * w.z; a0.w += v0 * w.w;
        a1.x += v1 * w.x; a1.y += v1 * w.y; a1.z += v1 * w.z; a1.w += v1 * w.w;
        a2.x += v2 * w.x; a2.y += v2 * w.y; a2.z += v2 * w.z; a2.w += v2 * w.w;
        a3.x += v3 * w.x; a3.y += v3 * w.y; a3.z += v3 * w.z; a3.w += v3 * w.w;
    }
    int row = (int)rowbase + r0;
    if (row + 0 < n) { float d = dis[row + 0];
        a0.x *= d; a0.y *= d; a0.z *= d; a0.w *= d;
        *(float4*)&T[(long long)(row + 0) * NH + c0] = a0; }
    if (row + 1 < n) { float d = dis[row + 1];
        a1.x *= d; a1.y *= d; a1.z *= d; a1.w *= d;
        *(float4*)&T[(long long)(row + 1) * NH + c0] = a1; }
    if (row + 2 < n) { float d = dis[row + 2];
        a2.x *= d; a2.y *= d; a2.z *= d; a2.w *= d;
        *(float4*)&T[(long long)(row + 2) * NH + c0] = a2; }
    if (row + 3 < n) { float d = dis[row + 3];
        a3.x *= d; a3.y *= d; a3.z *= d; a3.w *= d;
        *(float4*)&T[(long long)(row + 3) * NH + c0] = a3; }
}

// O[i] = dis[i]*(T[i] + sum_{s in bucket(i)} T[s]) + b   (wave per node).
// 8-deep gather unroll for MLP.
__global__ void __launch_bounds__(256) k_seg(
        const float* __restrict__ T, const int* __restrict__ esrc,
        const int* __restrict__ start, const int* __restrict__ cnt,
        const float* __restrict__ dis, const float* __restrict__ b,
        float* __restrict__ O, int n) {
    int lane = threadIdx.x & 63;
    int node = blockIdx.x * 4 + (threadIdx.x >> 6);
    if (node >= n) return;
    float di = dis[node];
    int g = cnt[node], st = start[node];
    float acc = T[(long long)node * NH + lane];   // self-loop term (pre-scaled)
    for (int base = 0; base < g; base += 64) {
        int m = g - base; if (m > 64) m = 64;
        int sIdx = (lane < m) ? esrc[st + base + lane] : 0;
        int j = 0;
        for (; j + 7 < m; j += 8) {
            int s0 = __shfl(sIdx, j, 64),   s1 = __shfl(sIdx, j+1, 64);
            int s2 = __shfl(sIdx, j+2, 64), s3 = __shfl(sIdx, j+3, 64);
            int s4 = __shfl(sIdx, j+4, 64), s5 = __shfl(sIdx, j+5, 64);
            int s6 = __shfl(sIdx, j+6, 64), s7 = __shfl(sIdx, j+7, 64);
            float v0 = T[(long long)s0 * NH + lane];
            float v1 = T[(long long)s1 * NH + lane];
            float v2 = T[(long long)s2 * NH + lane];
            float v3 = T[(long long)s3 * NH + lane];
            float v4 = T[(long long)s4 * NH + lane];
            float v5 = T[(long long)s5 * NH + lane];
            float v6 = T[(long long)s6 * NH + lane];
            float v7 = T[(long long)s7 * NH + lane];
            acc += v0; acc += v1; acc += v2; acc += v3;
            acc += v4; acc += v5; acc += v6; acc += v7;
        }
        for (; j < m; ++j)
            acc += T[(long long)__shfl(sIdx, j, 64) * NH + lane];
    }
    O[(long long)node * NH + lane] = di * acc + b[lane];
}

// t2'[i] = dis[i] * (tanh(z1[i]) @ W2)  (64x2)
__global__ void __launch_bounds__(256) k_gemm2(
        const float* __restrict__ z1, const float* __restrict__ W2,
        const float* __restrict__ dis, float2* __restrict__ t2, int n) {
    __shared__ float Ws[NH * 2];
    if (threadIdx.x < NH * 2) Ws[threadIdx.x] = W2[threadIdx.x];
    __syncthreads();
    int i = blockIdx.x * 256 + threadIdx.x;
    if (i >= n) return;
    const float4* zr = (const float4*)(z1 + (long long)i * NH);
    float a0 = 0.0f, a1 = 0.0f;
    #pragma unroll
    for (int k4 = 0; k4 < NH / 4; ++k4) {
        float4 z = zr[k4];
        float t;
        t = tanhf(z.x); a0 += t * Ws[(k4*4+0)*2]; a1 += t * Ws[(k4*4+0)*2+1];
        t = tanhf(z.y); a0 += t * Ws[(k4*4+1)*2]; a1 += t * Ws[(k4*4+1)*2+1];
        t = tanhf(z.z); a0 += t * Ws[(k4*4+2)*2]; a1 += t * Ws[(k4*4+2)*2+1];
        t = tanhf(z.w); a0 += t * Ws[(k4*4+3)*2]; a1 += t * Ws[(k4*4+3)*2+1];
    }
    float di = dis[i];
    t2[i] = make_float2(a0 * di, a1 * di);
}

// agg2[i] = dis[i]*(t2[i] + sum t2[s]) + b2   (thread per node, 4-deep MLP)
__global__ void __launch_bounds__(256) k_seg2(
        const float2* __restrict__ T2, const int* __restrict__ esrc,
        const int* __restrict__ start, const int* __restrict__ cnt,
        const float* __restrict__ dis, const float* __restrict__ b2,
        float2* __restrict__ O, int n) {
    int i = blockIdx.x * 256 + threadIdx.x;
    if (i >= n) return;
    float di = dis[i];
    int g = cnt[i], st = start[i];
    float2 self = T2[i];
    float a0 = self.x, a1 = self.y;
    int j = 0;
    for (; j + 3 < g; j += 4) {
        int e0 = esrc[st + j],     e1 = esrc[st + j + 1];
        int e2 = esrc[st + j + 2], e3 = esrc[st + j + 3];
        float2 v0 = T2[e0], v1 = T2[e1], v2 = T2[e2], v3 = T2[e3];
        a0 += v0.x + v1.x + v2.x + v3.x;
        a1 += v0.y + v1.y + v2.y + v3.y;
    }
    for (; j < g; ++j) {
        float2 v = T2[esrc[st + j]];
        a0 += v.x; a1 += v.y;
    }
    O[i] = make_float2(a0 * di + b2[0], a1 * di + b2[1]);
}

// emb = tanh(agg2) (agg2 aliases emb region); out = emb @ Wc + bc.
__global__ void __launch_bounds__(256) k_final(
        const float2* __restrict__ agg2, const float* __restrict__ Wc,
        const float* __restrict__ bc, float* __restrict__ out,
        float* __restrict__ emb, int n) {
    long long gid = (long long)blockIdx.x * 256 + threadIdx.x;
    int i = (int)(gid >> 4);
    int c = (int)(gid & 15);
    if (i >= n) return;
    float2 z = agg2[i];
    float e0 = tanhf(z.x), e1 = tanhf(z.y);
    out[(long long)i * 16 + c] = e0 * Wc[c] + e1 * Wc[16 + c] + bc[c];
    if (c == 0) emb[(long long)i * 2 + 0] = e0;
    if (c == 1) emb[(long long)i * 2 + 1] = e1;
}

extern "C" void kernel_launch(void* const* d_in, const int* in_sizes, int n_in,
                              void* d_out, int out_size, void* d_ws, size_t ws_size,
                              hipStream_t stream) {
    const float* x  = (const float*)d_in[0];
    const int*   ei = (const int*)  d_in[1];
    const float* W0 = (const float*)d_in[2];
    const float* b0 = (const float*)d_in[3];
    const float* W1 = (const float*)d_in[4];
    const float* b1 = (const float*)d_in[5];
    const float* W2 = (const float*)d_in[6];
    const float* b2 = (const float*)d_in[7];
    const float* Wc = (const float*)d_in[8];
    const float* bc = (const float*)d_in[9];

    int N = in_sizes[0] / NF;
    int E = in_sizes[1] / 2;

    float* out = (float*)d_out;                    // [N,16]
    float* emb = out + (long long)N * 16;          // [N,2]
    float2* t2   = (float2*)out;                   // scratch in out region
    float2* agg2 = (float2*)emb;                   // tanh'd in place by k_final

    // workspace: A[N*64] | B[N*64] | dis[N] | cnt[N] | start[N] | esrc[E] | fmt | gcount
    // rank[E] overlays A (A is dead until the GEMMs, which run after k_scatter).
    float* A      = (float*)d_ws;
    float* B      = A + (long long)N * NH;
    float* dis    = B + (long long)N * NH;
    int*   cnt    = (int*)(dis + N);
    int*   start  = cnt + N;
    int*   esrc   = start + N;
    int*   fmt    = esrc + E;
    int*   gcount = fmt + 1;
    int*   rank   = (int*)A;

    int nb_n   = (N + 255) / 256;
    int nb_e8  = (E + 256 * CE - 1) / (256 * CE);
    int nb_g   = (N + 63) / 64;
    int nb_s   = (N + 3) / 4;
    int nb_n16 = (int)(((long long)N * 16 + 255) / 256);

    // per-call bucketing (inputs restored before every call; same work each call)
    k_init    <<<nb_n, 256, 0, stream>>>(ei, fmt, cnt, gcount, N);
    k_cnt     <<<nb_e8, 256, 0, stream>>>(ei, fmt, cnt, rank, E);
    k_scan    <<<nb_n, 256, 0, stream>>>(cnt, start, dis, gcount, N);
    k_scatter <<<nb_e8, 256, 0, stream>>>(ei, fmt, start, rank, esrc, E);

    // layer 0 (no activation)
    k_gemm<NF><<<nb_g, 256, 0, stream>>>(x, W0, dis, A, N);
    k_seg     <<<nb_s, 256, 0, stream>>>(A, esrc, start, cnt, dis, b0, B, N);

    // layer 1 (tanh deferred into k_gemm2's read)
    k_gemm<NH><<<nb_g, 256, 0, stream>>>(B, W1, dis, A, N);
    k_seg     <<<nb_s, 256, 0, stream>>>(A, esrc, start, cnt, dis, b1, B, N);

    // layer 2 (2-wide) + head
    k_gemm2   <<<nb_n, 256, 0, stream>>>(B, W2, dis, t2, N);
    k_seg2    <<<nb_n, 256, 0, stream>>>(t2, esrc, start, cnt, dis, b2, agg2, N);
    k_final   <<<nb_n16, 256, 0, stream>>>(agg2, Wc, bc, out, emb, N);
}

// Round 6
// 389.388 us; speedup vs baseline: 1.0954x; 1.0954x over previous
//
#include <hip/hip_runtime.h>

// GCN forward: 3x GCNConv (128->64->64->2) + linear head (2->16).
// N=100000 nodes, E=1600000 edges (+self-loops handled analytically).
// Preprocessing: two-level LDS bucket sort (coarse 256-node buckets, then
// per-bucket fine sort entirely in LDS). Global returning atomics (the ~23G/s
// per-CU-queue wall seen in k_cnt) are replaced by LDS atomics; the only
// global atomics left are 400k space-reservations on 391 line-padded counters.
// dis[] is pre-folded into transform outputs: T'[v] = dis[v]*t[v], so
// O[i] = dis[i]*(T'[i] + sum_{s in bucket(i)} T'[s]) + b.

#define NF 128
#define NH 64
#define NPB 256      // nodes per coarse bucket (bucket = dst >> 8)
#define MAXNB 512    // max coarse buckets (N < 131072, matches 17-bit src pack)
#define CAP 6144     // max edges per coarse bucket (mean 4096, >30 sigma)
#define A1G 1024     // grid for coarse count/scatter (must match between them)

// Zero coarse counters + detect int64 vs int32 edge_index layout.
__global__ void k_init0(const int* __restrict__ ei, int* __restrict__ fmt,
                        int* __restrict__ ccnt, int nb16) {
    int i = blockIdx.x * 256 + threadIdx.x;
    if (i < nb16) ccnt[i] = 0;
    if (i == 0) {
        int f = 1;
        #pragma unroll
        for (int k = 1; k < 32; k += 2) if (ei[k] != 0) f = 0;
        *fmt = f;   // 1 => int64 (stride 2 in int32 words), 0 => int32
    }
}

// Coarse count: LDS histogram per block, then reserve per-(block,bucket) space
// with ONE padded global atomic per bucket per block. ccnt stride 16 ints keeps
// each counter on its own 64B line (contention is line-parallel).
__global__ void __launch_bounds__(256) k_coarse(
        const int* __restrict__ ei, const int* __restrict__ fmt,
        int* __restrict__ ccnt, int* __restrict__ blockbase, int E, int NB) {
    __shared__ int h[MAXNB];
    int sh = *fmt;
    for (int i = threadIdx.x; i < NB; i += 256) h[i] = 0;
    __syncthreads();
    for (long long e = (long long)blockIdx.x * 256 + threadIdx.x; e < E;
         e += (long long)A1G * 256) {
        int d = ei[(long long)(E + e) << sh];
        atomicAdd(&h[d >> 8], 1);
    }
    __syncthreads();
    for (int b = threadIdx.x; b < NB; b += 256) {
        int c = h[b];
        int base = (c > 0) ? atomicAdd(&ccnt[b * 16], c) : 0;
        blockbase[(long long)blockIdx.x * NB + b] = base;
    }
}

// Exclusive scan of the NB coarse counts (single block).
__global__ void __launch_bounds__(512) k_cscan(
        const int* __restrict__ ccnt, int* __restrict__ cstart, int NB) {
    __shared__ int s[512];
    int t = threadIdx.x;
    int c = (t < NB) ? ccnt[t * 16] : 0;
    s[t] = c;
    __syncthreads();
    for (int off = 1; off < 512; off <<= 1) {
        int v = s[t];
        int u = (t >= off) ? s[t - off] : 0;
        __syncthreads();
        s[t] = v + u;
        __syncthreads();
    }
    if (t < NB) cstart[t] = s[t] - c;
}

// Coarse scatter: same grid + same grid-stride partition as k_coarse, so this
// block's per-bucket edge totals equal its reservation. Local ranks via LDS
// returning atomics. Edge packed as src | (dst&255)<<17  (src < 2^17).
__global__ void __launch_bounds__(256) k_cscatter(
        const int* __restrict__ ei, const int* __restrict__ fmt,
        const int* __restrict__ cstart, const int* __restrict__ blockbase,
        int* __restrict__ pairs, int E, int NB) {
    __shared__ int h[MAXNB];
    int sh = *fmt;
    for (int i = threadIdx.x; i < NB; i += 256) h[i] = 0;
    __syncthreads();
    for (long long e = (long long)blockIdx.x * 256 + threadIdx.x; e < E;
         e += (long long)A1G * 256) {
        int s = ei[(long long)e << sh];
        int d = ei[(long long)(E + e) << sh];
        int b = d >> 8;
        int r = atomicAdd(&h[b], 1);
        pairs[cstart[b] + blockbase[(long long)blockIdx.x * NB + b] + r]
            = s | ((d & 255) << 17);
    }
}

// Fine sort: one block per coarse bucket, entirely in LDS. Global node starts
// are cstart[b] + local prefix (no global scan needed). Emits cnt/start/dis
// (coalesced) and esrc (scatter within the bucket's contiguous window).
__global__ void __launch_bounds__(256) k_bucket(
        const int* __restrict__ pairs, const int* __restrict__ ccnt,
        const int* __restrict__ cstart, int* __restrict__ esrc,
        int* __restrict__ cnt, int* __restrict__ start, float* __restrict__ dis,
        int N) {
    __shared__ int words[CAP];
    __shared__ unsigned char rk[CAP];
    __shared__ int h[NPB];
    __shared__ int hs[NPB];
    int b = blockIdx.x;
    int cs = cstart[b];
    int ec = ccnt[b * 16];
    if (ec > CAP) ec = CAP;          // memory-safety clamp (P ~ 0 for uniform dst)
    int t = threadIdx.x;
    for (int i = t; i < ec; i += 256) words[i] = pairs[cs + i];
    h[t] = 0;
    __syncthreads();
    for (int i = t; i < ec; i += 256) {
        int ld = words[i] >> 17;
        rk[i] = (unsigned char)atomicAdd(&h[ld], 1);
    }
    __syncthreads();
    int c = h[t];
    hs[t] = c;
    __syncthreads();
    for (int off = 1; off < 256; off <<= 1) {
        int v = hs[t];
        int u = (t >= off) ? hs[t - off] : 0;
        __syncthreads();
        hs[t] = v + u;               // inclusive scan
        __syncthreads();
    }
    int node = b * NPB + t;
    if (node < N) {
        cnt[node] = c;
        start[node] = cs + hs[t] - c;
        dis[node] = rsqrtf(1.0f + (float)c);   // degree includes self-loop
    }
    for (int i = t; i < ec; i += 256) {
        int w = words[i];
        int ld = w >> 17;
        esrc[cs + (hs[ld] - h[ld]) + rk[i]] = w & 0x1FFFF;
    }
}

// T[n,NH] = dis[n] * (X[n,K] @ W[K,NH]).
// 64 rows/block, 256 threads, 4 rows x 4 cols per thread (16 acc).
template<int K>
__global__ void __launch_bounds__(256) k_gemm(
        const float* __restrict__ X, const float* __restrict__ W,
        const float* __restrict__ dis, float* __restrict__ T, int n) {
    constexpr int KP = K + 4;
    __shared__ float xs[64 * KP];
    __shared__ float Ws[K * NH];
    for (int i = threadIdx.x; i < K * NH / 4; i += 256)
        ((float4*)Ws)[i] = ((const float4*)W)[i];
    long long rowbase = (long long)blockIdx.x * 64;
    const float4* X4 = (const float4*)(X + rowbase * K);
    long long lim4 = ((long long)n * K - rowbase * K) >> 2;  // remaining float4s
    for (int i = threadIdx.x; i < 16 * K; i += 256) {
        float4 v = (i < lim4) ? X4[i] : make_float4(0.f, 0.f, 0.f, 0.f);
        int r = i / (K / 4), kk = (i % (K / 4)) * 4;
        *(float4*)&xs[r * KP + kk] = v;
    }
    __syncthreads();
    int c0 = (threadIdx.x & 15) * 4;
    int r0 = (threadIdx.x >> 4) * 4;
    const float* x0 = &xs[(r0 + 0) * KP];
    const float* x1 = &xs[(r0 + 1) * KP];
    const float* x2 = &xs[(r0 + 2) * KP];
    const float* x3 = &xs[(r0 + 3) * KP];
    float4 a0{0,0,0,0}, a1{0,0,0,0}, a2{0,0,0,0}, a3{0,0,0,0};
    #pragma unroll 4
    for (int k = 0; k < K; ++k) {
        float4 w = *(const float4*)&Ws[k * NH + c0];
        float v0 = x0[k], v1 = x1[k], v2 = x2[k], v3 = x3[k];
        a0.x += v0 * w.x; a0.y += v0 * w.y; a0.z += v0 * w.z; a0.w += v0 * w.w;
        a1.x += v1 * w.x; a1.y += v1 * w.y; a1.z += v1 * w.z; a1.w += v1 * w.w;
        a2.x += v2 * w.x; a2.y += v2 * w.y; a2.z += v2 * w.z; a2.w += v2 * w.w;
        a3.x += v3 * w.x; a3.y += v3 * w.y; a3.z += v3 * w.z; a3.w += v3 * w.w;
    }
    int row = (int)rowbase + r0;
    if (row + 0 < n) { float d = dis[row + 0];
        a0.x *= d; a0.y *= d; a0.z *= d; a0.w *= d;
        *(float4*)&T[(long long)(row + 0) * NH + c0] = a0; }
    if (row + 1 < n) { float d = dis[row + 1];
        a1.x *= d; a1.y *= d; a1.z *= d; a1.w *= d;
        *(float4*)&T[(long long)(row + 1) * NH + c0] = a1; }
    if (row + 2 < n) { float d = dis[row + 2];
        a2.x *= d; a2.y *= d; a2.z *= d; a2.w *= d;
        *(float4*)&T[(long long)(row + 2) * NH + c0] = a2; }
    if (row + 3 < n) { float d = dis[row + 3];
        a3.x *= d; a3.y *= d; a3.z *= d; a3.w *= d;
        *(float4*)&T[(long long)(row + 3) * NH + c0] = a3; }
}

// O[i] = dis[i]*(T[i] + sum_{s in bucket(i)} T[s]) + b   (wave per node).
__global__ void __launch_bounds__(256) k_seg(
        const float* __restrict__ T, const int* __restrict__ esrc,
        const int* __restrict__ start, const int* __restrict__ cnt,
        const float* __restrict__ dis, const float* __restrict__ b,
        float* __restrict__ O, int n) {
    int lane = threadIdx.x & 63;
    int node = blockIdx.x * 4 + (threadIdx.x >> 6);
    if (node >= n) return;
    float di = dis[node];
    int g = cnt[node], st = start[node];
    float acc = T[(long long)node * NH + lane];   // self-loop term (pre-scaled)
    for (int base = 0; base < g; base += 64) {
        int m = g - base; if (m > 64) m = 64;
        int sIdx = (lane < m) ? esrc[st + base + lane] : 0;
        int j = 0;
        for (; j + 7 < m; j += 8) {
            int s0 = __shfl(sIdx, j, 64),   s1 = __shfl(sIdx, j+1, 64);
            int s2 = __shfl(sIdx, j+2, 64), s3 = __shfl(sIdx, j+3, 64);
            int s4 = __shfl(sIdx, j+4, 64), s5 = __shfl(sIdx, j+5, 64);
            int s6 = __shfl(sIdx, j+6, 64), s7 = __shfl(sIdx, j+7, 64);
            float v0 = T[(long long)s0 * NH + lane];
            float v1 = T[(long long)s1 * NH + lane];
            float v2 = T[(long long)s2 * NH + lane];
            float v3 = T[(long long)s3 * NH + lane];
            float v4 = T[(long long)s4 * NH + lane];
            float v5 = T[(long long)s5 * NH + lane];
            float v6 = T[(long long)s6 * NH + lane];
            float v7 = T[(long long)s7 * NH + lane];
            acc += v0; acc += v1; acc += v2; acc += v3;
            acc += v4; acc += v5; acc += v6; acc += v7;
        }
        for (; j < m; ++j)
            acc += T[(long long)__shfl(sIdx, j, 64) * NH + lane];
    }
    O[(long long)node * NH + lane] = di * acc + b[lane];
}

// t2'[i] = dis[i] * (tanh(z1[i]) @ W2)  (64x2)
__global__ void __launch_bounds__(256) k_gemm2(
        const float* __restrict__ z1, const float* __restrict__ W2,
        const float* __restrict__ dis, float2* __restrict__ t2, int n) {
    __shared__ float Ws[NH * 2];
    if (threadIdx.x < NH * 2) Ws[threadIdx.x] = W2[threadIdx.x];
    __syncthreads();
    int i = blockIdx.x * 256 + threadIdx.x;
    if (i >= n) return;
    const float4* zr = (const float4*)(z1 + (long long)i * NH);
    float a0 = 0.0f, a1 = 0.0f;
    #pragma unroll
    for (int k4 = 0; k4 < NH / 4; ++k4) {
        float4 z = zr[k4];
        float t;
        t = tanhf(z.x); a0 += t * Ws[(k4*4+0)*2]; a1 += t * Ws[(k4*4+0)*2+1];
        t = tanhf(z.y); a0 += t * Ws[(k4*4+1)*2]; a1 += t * Ws[(k4*4+1)*2+1];
        t = tanhf(z.z); a0 += t * Ws[(k4*4+2)*2]; a1 += t * Ws[(k4*4+2)*2+1];
        t = tanhf(z.w); a0 += t * Ws[(k4*4+3)*2]; a1 += t * Ws[(k4*4+3)*2+1];
    }
    float di = dis[i];
    t2[i] = make_float2(a0 * di, a1 * di);
}

// agg2[i] = dis[i]*(t2[i] + sum t2[s]) + b2   (thread per node, 4-deep MLP)
__global__ void __launch_bounds__(256) k_seg2(
        const float2* __restrict__ T2, const int* __restrict__ esrc,
        const int* __restrict__ start, const int* __restrict__ cnt,
        const float* __restrict__ dis, const float* __restrict__ b2,
        float2* __restrict__ O, int n) {
    int i = blockIdx.x * 256 + threadIdx.x;
    if (i >= n) return;
    float di = dis[i];
    int g = cnt[i], st = start[i];
    float2 self = T2[i];
    float a0 = self.x, a1 = self.y;
    int j = 0;
    for (; j + 3 < g; j += 4) {
        int e0 = esrc[st + j],     e1 = esrc[st + j + 1];
        int e2 = esrc[st + j + 2], e3 = esrc[st + j + 3];
        float2 v0 = T2[e0], v1 = T2[e1], v2 = T2[e2], v3 = T2[e3];
        a0 += v0.x + v1.x + v2.x + v3.x;
        a1 += v0.y + v1.y + v2.y + v3.y;
    }
    for (; j < g; ++j) {
        float2 v = T2[esrc[st + j]];
        a0 += v.x; a1 += v.y;
    }
    O[i] = make_float2(a0 * di + b2[0], a1 * di + b2[1]);
}

// emb = tanh(agg2) (agg2 aliases emb region); out = emb @ Wc + bc.
__global__ void __launch_bounds__(256) k_final(
        const float2* __restrict__ agg2, const float* __restrict__ Wc,
        const float* __restrict__ bc, float* __restrict__ out,
        float* __restrict__ emb, int n) {
    long long gid = (long long)blockIdx.x * 256 + threadIdx.x;
    int i = (int)(gid >> 4);
    int c = (int)(gid & 15);
    if (i >= n) return;
    float2 z = agg2[i];
    float e0 = tanhf(z.x), e1 = tanhf(z.y);
    out[(long long)i * 16 + c] = e0 * Wc[c] + e1 * Wc[16 + c] + bc[c];
    if (c == 0) emb[(long long)i * 2 + 0] = e0;
    if (c == 1) emb[(long long)i * 2 + 1] = e1;
}

extern "C" void kernel_launch(void* const* d_in, const int* in_sizes, int n_in,
                              void* d_out, int out_size, void* d_ws, size_t ws_size,
                              hipStream_t stream) {
    const float* x  = (const float*)d_in[0];
    const int*   ei = (const int*)  d_in[1];
    const float* W0 = (const float*)d_in[2];
    const float* b0 = (const float*)d_in[3];
    const float* W1 = (const float*)d_in[4];
    const float* b1 = (const float*)d_in[5];
    const float* W2 = (const float*)d_in[6];
    const float* b2 = (const float*)d_in[7];
    const float* Wc = (const float*)d_in[8];
    const float* bc = (const float*)d_in[9];

    int N = in_sizes[0] / NF;
    int E = in_sizes[1] / 2;
    int NB = (N + NPB - 1) / NPB;   // 391 for N=100000 (must be <= MAXNB)

    float* out = (float*)d_out;                    // [N,16]
    float* emb = out + (long long)N * 16;          // [N,2]
    float2* t2   = (float2*)out;                   // scratch in out region
    float2* agg2 = (float2*)emb;                   // tanh'd in place by k_final

    // workspace: A[N*64] | B[N*64] | dis[N] | cnt[N] | start[N] | esrc[E]
    // Preprocessing scratch (pairs/blockbase/ccnt/cstart/fmt) overlays A,
    // which is dead until k_gemm<NF> (runs after k_bucket).
    float* A      = (float*)d_ws;
    float* Bb     = A + (long long)N * NH;
    float* dis    = Bb + (long long)N * NH;
    int*   cnt    = (int*)(dis + N);
    int*   start  = cnt + N;
    int*   esrc   = start + N;

    int* pairs     = (int*)A;                       // E
    int* blockbase = pairs + E;                     // A1G * NB
    int* ccnt      = blockbase + (long long)A1G * NB;  // NB*16 (line-padded)
    int* cstart    = ccnt + NB * 16;                // NB
    int* fmt       = cstart + NB;                   // 1

    int nb_n   = (N + 255) / 256;
    int nb_g   = (N + 63) / 64;
    int nb_s   = (N + 3) / 4;
    int nb_n16 = (int)(((long long)N * 16 + 255) / 256);
    int nb_i0  = (NB * 16 + 255) / 256;

    // per-call two-level bucket sort (inputs restored before every call)
    k_init0   <<<nb_i0, 256, 0, stream>>>(ei, fmt, ccnt, NB * 16);
    k_coarse  <<<A1G, 256, 0, stream>>>(ei, fmt, ccnt, blockbase, E, NB);
    k_cscan   <<<1, 512, 0, stream>>>(ccnt, cstart, NB);
    k_cscatter<<<A1G, 256, 0, stream>>>(ei, fmt, cstart, blockbase, pairs, E, NB);
    k_bucket  <<<NB, 256, 0, stream>>>(pairs, ccnt, cstart, esrc, cnt, start, dis, N);

    // layer 0 (no activation)
    k_gemm<NF><<<nb_g, 256, 0, stream>>>(x, W0, dis, A, N);
    k_seg     <<<nb_s, 256, 0, stream>>>(A, esrc, start, cnt, dis, b0, Bb, N);

    // layer 1 (tanh deferred into k_gemm2's read)
    k_gemm<NH><<<nb_g, 256, 0, stream>>>(Bb, W1, dis, A, N);
    k_seg     <<<nb_s, 256, 0, stream>>>(A, esrc, start, cnt, dis, b1, Bb, N);

    // layer 2 (2-wide) + head
    k_gemm2   <<<nb_n, 256, 0, stream>>>(Bb, W2, dis, t2, N);
    k_seg2    <<<nb_n, 256, 0, stream>>>(t2, esrc, start, cnt, dis, b2, agg2, N);
    k_final   <<<nb_n16, 256, 0, stream>>>(agg2, Wc, bc, out, emb, N);
}

// Round 10
// 385.152 us; speedup vs baseline: 1.1075x; 1.0110x over previous
//
#include <hip/hip_runtime.h>

// GCN forward: 3x GCNConv (128->64->64->2) + linear head (2->16).
// N=100000 nodes, E=1600000 edges (+self-loops handled analytically).
// Preprocessing: two-level LDS bucket sort (coarse 256-node buckets, then
// per-bucket fine sort entirely in LDS) - avoids the ~24G/s global returning-
// atomic wall. Aggregation: atomic-free fp32 segment-sum gathers (wave/node).
// NOTE: 16-bit T storage (fp16 / int16-global / int16-rowwise) was tried in
// rounds 7-9; all three land at ~3e-3 absmax vs the 2.66e-3 threshold despite
// wildly different quantization step sizes - fp32 gathers are the only
// configuration with validated margin (2.44e-4). dis[] pre-folded:
// T'[v]=dis[v]*t[v], so O[i]=dis[i]*(T'[i]+sum_{s in bucket(i)} T'[s])+b.
// This round: k_seg2+k_final fused (t2 relocated to dead T region to avoid
// read/write aliasing with d_out).

#define NF 128
#define NH 64
#define NPB 256      // nodes per coarse bucket (bucket = dst >> 8)
#define MAXNB 512    // max coarse buckets (N < 131072, matches 17-bit src pack)
#define CAP 6144     // max edges per coarse bucket (mean 4096, >30 sigma)
#define A1G 1024     // grid for coarse count/scatter (must match between them)

// Zero coarse counters + detect int64 vs int32 edge_index layout.
__global__ void k_init0(const int* __restrict__ ei, int* __restrict__ fmt,
                        int* __restrict__ ccnt, int nb16) {
    int i = blockIdx.x * 256 + threadIdx.x;
    if (i < nb16) ccnt[i] = 0;
    if (i == 0) {
        int f = 1;
        #pragma unroll
        for (int k = 1; k < 32; k += 2) if (ei[k] != 0) f = 0;
        *fmt = f;   // 1 => int64 (stride 2 in int32 words), 0 => int32
    }
}

// Coarse count: LDS histogram per block, then reserve per-(block,bucket) space
// with ONE padded global atomic per bucket per block (line-parallel).
__global__ void __launch_bounds__(256) k_coarse(
        const int* __restrict__ ei, const int* __restrict__ fmt,
        int* __restrict__ ccnt, int* __restrict__ blockbase, int E, int NB) {
    __shared__ int h[MAXNB];
    int sh = *fmt;
    for (int i = threadIdx.x; i < NB; i += 256) h[i] = 0;
    __syncthreads();
    for (long long e = (long long)blockIdx.x * 256 + threadIdx.x; e < E;
         e += (long long)A1G * 256) {
        int d = ei[(long long)(E + e) << sh];
        atomicAdd(&h[d >> 8], 1);
    }
    __syncthreads();
    for (int b = threadIdx.x; b < NB; b += 256) {
        int c = h[b];
        int base = (c > 0) ? atomicAdd(&ccnt[b * 16], c) : 0;
        blockbase[(long long)blockIdx.x * NB + b] = base;
    }
}

// Exclusive scan of the NB coarse counts (single block).
__global__ void __launch_bounds__(512) k_cscan(
        const int* __restrict__ ccnt, int* __restrict__ cstart, int NB) {
    __shared__ int s[512];
    int t = threadIdx.x;
    int c = (t < NB) ? ccnt[t * 16] : 0;
    s[t] = c;
    __syncthreads();
    for (int off = 1; off < 512; off <<= 1) {
        int v = s[t];
        int u = (t >= off) ? s[t - off] : 0;
        __syncthreads();
        s[t] = v + u;
        __syncthreads();
    }
    if (t < NB) cstart[t] = s[t] - c;
}

// Coarse scatter: same grid-stride partition as k_coarse, so this block's
// per-bucket totals equal its reservation. Local ranks via LDS atomics.
// Edge packed as src | (dst&255)<<17  (src < 2^17).
__global__ void __launch_bounds__(256) k_cscatter(
        const int* __restrict__ ei, const int* __restrict__ fmt,
        const int* __restrict__ cstart, const int* __restrict__ blockbase,
        int* __restrict__ pairs, int E, int NB) {
    __shared__ int h[MAXNB];
    int sh = *fmt;
    for (int i = threadIdx.x; i < NB; i += 256) h[i] = 0;
    __syncthreads();
    for (long long e = (long long)blockIdx.x * 256 + threadIdx.x; e < E;
         e += (long long)A1G * 256) {
        int s = ei[(long long)e << sh];
        int d = ei[(long long)(E + e) << sh];
        int b = d >> 8;
        int r = atomicAdd(&h[b], 1);
        pairs[cstart[b] + blockbase[(long long)blockIdx.x * NB + b] + r]
            = s | ((d & 255) << 17);
    }
}

// Fine sort: one block per coarse bucket, entirely in LDS. Emits cnt/start/dis
// (coalesced) and esrc (scatter within the bucket's contiguous window).
__global__ void __launch_bounds__(256) k_bucket(
        const int* __restrict__ pairs, const int* __restrict__ ccnt,
        const int* __restrict__ cstart, int* __restrict__ esrc,
        int* __restrict__ cnt, int* __restrict__ start, float* __restrict__ dis,
        int N) {
    __shared__ int words[CAP];
    __shared__ unsigned char rk[CAP];
    __shared__ int h[NPB];
    __shared__ int hs[NPB];
    int b = blockIdx.x;
    int cs = cstart[b];
    int ec = ccnt[b * 16];
    if (ec > CAP) ec = CAP;          // memory-safety clamp (P ~ 0 for uniform dst)
    int t = threadIdx.x;
    for (int i = t; i < ec; i += 256) words[i] = pairs[cs + i];
    h[t] = 0;
    __syncthreads();
    for (int i = t; i < ec; i += 256) {
        int ld = words[i] >> 17;
        rk[i] = (unsigned char)atomicAdd(&h[ld], 1);
    }
    __syncthreads();
    int c = h[t];
    hs[t] = c;
    __syncthreads();
    for (int off = 1; off < 256; off <<= 1) {
        int v = hs[t];
        int u = (t >= off) ? hs[t - off] : 0;
        __syncthreads();
        hs[t] = v + u;               // inclusive scan
        __syncthreads();
    }
    int node = b * NPB + t;
    if (node < N) {
        cnt[node] = c;
        start[node] = cs + hs[t] - c;
        dis[node] = rsqrtf(1.0f + (float)c);   // degree includes self-loop
    }
    for (int i = t; i < ec; i += 256) {
        int w = words[i];
        int ld = w >> 17;
        esrc[cs + (hs[ld] - h[ld]) + rk[i]] = w & 0x1FFFF;
    }
}

// T[n,NH] = dis[n] * (X[n,K] @ W[K,NH]).
// 64 rows/block, 256 threads, 4 rows x 4 cols per thread (16 acc).
template<int K>
__global__ void __launch_bounds__(256) k_gemm(
        const float* __restrict__ X, const float* __restrict__ W,
        const float* __restrict__ dis, float* __restrict__ T, int n) {
    constexpr int KP = K + 4;
    __shared__ float xs[64 * KP];
    __shared__ float Ws[K * NH];
    for (int i = threadIdx.x; i < K * NH / 4; i += 256)
        ((float4*)Ws)[i] = ((const float4*)W)[i];
    long long rowbase = (long long)blockIdx.x * 64;
    const float4* X4 = (const float4*)(X + rowbase * K);
    long long lim4 = ((long long)n * K - rowbase * K) >> 2;  // remaining float4s
    for (int i = threadIdx.x; i < 16 * K; i += 256) {
        float4 v = (i < lim4) ? X4[i] : make_float4(0.f, 0.f, 0.f, 0.f);
        int r = i / (K / 4), kk = (i % (K / 4)) * 4;
        *(float4*)&xs[r * KP + kk] = v;
    }
    __syncthreads();
    int c0 = (threadIdx.x & 15) * 4;
    int r0 = (threadIdx.x >> 4) * 4;
    const float* x0 = &xs[(r0 + 0) * KP];
    const float* x1 = &xs[(r0 + 1) * KP];
    const float* x2 = &xs[(r0 + 2) * KP];
    const float* x3 = &xs[(r0 + 3) * KP];
    float4 a0{0,0,0,0}, a1{0,0,0,0}, a2{0,0,0,0}, a3{0,0,0,0};
    #pragma unroll 4
    for (int k = 0; k < K; ++k) {
        float4 w = *(const float4*)&Ws[k * NH + c0];
        float v0 = x0[k], v1 = x1[k], v2 = x2[k], v3 = x3[k];
        a0.x += v0 * w.x; a0.y += v0 * w.y; a0.z += v0 * w.z; a0.w += v0 * w.w;
        a1.x += v1 * w.x; a1.y += v1 * w.y; a1.z += v1 * w.z; a1.w += v1 * w.w;
        a2.x += v2 * w.x; a2.y += v2 * w.y; a2.z += v2 * w.z; a2.w += v2 * w.w;
        a3.x += v3 * w.x; a3.y += v3 * w.y; a3.z += v3 * w.z; a3.w += v3 * w.w;
    }
    int row = (int)rowbase + r0;
    if (row + 0 < n) { float d = dis[row + 0];
        a0.x *= d; a0.y *= d; a0.z *= d; a0.w *= d;
        *(float4*)&T[(long long)(row + 0) * NH + c0] = a0; }
    if (row + 1 < n) { float d = dis[row + 1];
        a1.x *= d; a1.y *= d; a1.z *= d; a1.w *= d;
        *(float4*)&T[(long long)(row + 1) * NH + c0] = a1; }
    if (row + 2 < n) { float d = dis[row + 2];
        a2.x *= d; a2.y *= d; a2.z *= d; a2.w *= d;
        *(float4*)&T[(long long)(row + 2) * NH + c0] = a2; }
    if (row + 3 < n) { float d = dis[row + 3];
        a3.x *= d; a3.y *= d; a3.z *= d; a3.w *= d;
        *(float4*)&T[(long long)(row + 3) * NH + c0] = a3; }
}

// O[i] = dis[i]*(T[i] + sum_{s in bucket(i)} T[s]) + b   (wave per node).
// 8-deep gather unroll for MLP.
__global__ void __launch_bounds__(256) k_seg(
        const float* __restrict__ T, const int* __restrict__ esrc,
        const int* __restrict__ start, const int* __restrict__ cnt,
        const float* __restrict__ dis, const float* __restrict__ b,
        float* __restrict__ O, int n) {
    int lane = threadIdx.x & 63;
    int node = blockIdx.x * 4 + (threadIdx.x >> 6);
    if (node >= n) return;
    float di = dis[node];
    int g = cnt[node], st = start[node];
    float acc = T[(long long)node * NH + lane];   // self-loop term (pre-scaled)
    for (int base = 0; base < g; base += 64) {
        int m = g - base; if (m > 64) m = 64;
        int sIdx = (lane < m) ? esrc[st + base + lane] : 0;
        int j = 0;
        for (; j + 7 < m; j += 8) {
            int s0 = __shfl(sIdx, j, 64),   s1 = __shfl(sIdx, j+1, 64);
            int s2 = __shfl(sIdx, j+2, 64), s3 = __shfl(sIdx, j+3, 64);
            int s4 = __shfl(sIdx, j+4, 64), s5 = __shfl(sIdx, j+5, 64);
            int s6 = __shfl(sIdx, j+6, 64), s7 = __shfl(sIdx, j+7, 64);
            float v0 = T[(long long)s0 * NH + lane];
            float v1 = T[(long long)s1 * NH + lane];
            float v2 = T[(long long)s2 * NH + lane];
            float v3 = T[(long long)s3 * NH + lane];
            float v4 = T[(long long)s4 * NH + lane];
            float v5 = T[(long long)s5 * NH + lane];
            float v6 = T[(long long)s6 * NH + lane];
            float v7 = T[(long long)s7 * NH + lane];
            acc += v0; acc += v1; acc += v2; acc += v3;
            acc += v4; acc += v5; acc += v6; acc += v7;
        }
        for (; j < m; ++j)
            acc += T[(long long)__shfl(sIdx, j, 64) * NH + lane];
    }
    O[(long long)node * NH + lane] = di * acc + b[lane];
}

// t2'[i] = dis[i] * (tanh(z1[i]) @ W2)  (64x2)
__global__ void __launch_bounds__(256) k_gemm2(
        const float* __restrict__ z1, const float* __restrict__ W2,
        const float* __restrict__ dis, float2* __restrict__ t2, int n) {
    __shared__ float Ws[NH * 2];
    if (threadIdx.x < NH * 2) Ws[threadIdx.x] = W2[threadIdx.x];
    __syncthreads();
    int i = blockIdx.x * 256 + threadIdx.x;
    if (i >= n) return;
    const float4* zr = (const float4*)(z1 + (long long)i * NH);
    float a0 = 0.0f, a1 = 0.0f;
    #pragma unroll
    for (int k4 = 0; k4 < NH / 4; ++k4) {
        float4 z = zr[k4];
        float t;
        t = tanhf(z.x); a0 += t * Ws[(k4*4+0)*2]; a1 += t * Ws[(k4*4+0)*2+1];
        t = tanhf(z.y); a0 += t * Ws[(k4*4+1)*2]; a1 += t * Ws[(k4*4+1)*2+1];
        t = tanhf(z.z); a0 += t * Ws[(k4*4+2)*2]; a1 += t * Ws[(k4*4+2)*2+1];
        t = tanhf(z.w); a0 += t * Ws[(k4*4+3)*2]; a1 += t * Ws[(k4*4+3)*2+1];
    }
    float di = dis[i];
    t2[i] = make_float2(a0 * di, a1 * di);
}

// Fused layer-2 aggregation + head (was k_seg2 + k_final):
// agg2 = dis[i]*(t2[i] + sum t2[s]) + b2; emb = tanh(agg2);
// out[i,c] = emb0*Wc[0,c] + emb1*Wc[1,c] + bc[c].
// t2 lives in the (dead) T region, so out/emb writes cannot alias reads.
__global__ void __launch_bounds__(256) k_seg2f(
        const float2* __restrict__ T2, const int* __restrict__ esrc,
        const int* __restrict__ start, const int* __restrict__ cnt,
        const float* __restrict__ dis, const float* __restrict__ b2,
        const float* __restrict__ Wc, const float* __restrict__ bc,
        float* __restrict__ out, float* __restrict__ emb, int n) {
    __shared__ float Wcs[32];
    __shared__ float bcs[16];
    if (threadIdx.x < 32) Wcs[threadIdx.x] = Wc[threadIdx.x];
    if (threadIdx.x < 16) bcs[threadIdx.x] = bc[threadIdx.x];
    __syncthreads();
    int i = blockIdx.x * 256 + threadIdx.x;
    if (i >= n) return;
    float di = dis[i];
    int g = cnt[i], st = start[i];
    float2 self = T2[i];
    float a0 = self.x, a1 = self.y;
    int j = 0;
    for (; j + 7 < g; j += 8) {
        int e0 = esrc[st+j],   e1 = esrc[st+j+1], e2 = esrc[st+j+2], e3 = esrc[st+j+3];
        int e4 = esrc[st+j+4], e5 = esrc[st+j+5], e6 = esrc[st+j+6], e7 = esrc[st+j+7];
        float2 v0 = T2[e0], v1 = T2[e1], v2 = T2[e2], v3 = T2[e3];
        float2 v4 = T2[e4], v5 = T2[e5], v6 = T2[e6], v7 = T2[e7];
        a0 += v0.x + v1.x + v2.x + v3.x + v4.x + v5.x + v6.x + v7.x;
        a1 += v0.y + v1.y + v2.y + v3.y + v4.y + v5.y + v6.y + v7.y;
    }
    for (; j < g; ++j) {
        float2 v = T2[esrc[st + j]];
        a0 += v.x; a1 += v.y;
    }
    float e0 = tanhf(a0 * di + b2[0]);
    float e1 = tanhf(a1 * di + b2[1]);
    *(float2*)&emb[(long long)i * 2] = make_float2(e0, e1);
    float* op = &out[(long long)i * 16];
    #pragma unroll
    for (int c4 = 0; c4 < 4; ++c4) {
        float4 o;
        o.x = e0 * Wcs[c4*4+0] + e1 * Wcs[16 + c4*4+0] + bcs[c4*4+0];
        o.y = e0 * Wcs[c4*4+1] + e1 * Wcs[16 + c4*4+1] + bcs[c4*4+1];
        o.z = e0 * Wcs[c4*4+2] + e1 * Wcs[16 + c4*4+2] + bcs[c4*4+2];
        o.w = e0 * Wcs[c4*4+3] + e1 * Wcs[16 + c4*4+3] + bcs[c4*4+3];
        *(float4*)&op[c4 * 4] = o;
    }
}

extern "C" void kernel_launch(void* const* d_in, const int* in_sizes, int n_in,
                              void* d_out, int out_size, void* d_ws, size_t ws_size,
                              hipStream_t stream) {
    const float* x  = (const float*)d_in[0];
    const int*   ei = (const int*)  d_in[1];
    const float* W0 = (const float*)d_in[2];
    const float* b0 = (const float*)d_in[3];
    const float* W1 = (const float*)d_in[4];
    const float* b1 = (const float*)d_in[5];
    const float* W2 = (const float*)d_in[6];
    const float* b2 = (const float*)d_in[7];
    const float* Wc = (const float*)d_in[8];
    const float* bc = (const float*)d_in[9];

    int N = in_sizes[0] / NF;
    int E = in_sizes[1] / 2;
    int NB = (N + NPB - 1) / NPB;   // 391 for N=100000 (must be <= MAXNB)

    float* out = (float*)d_out;                    // [N,16]
    float* emb = out + (long long)N * 16;          // [N,2]

    // workspace: A[N*64] | Bb[N*64] | dis[N] | cnt[N] | start[N] | esrc[E] | fmt
    // Preprocessing scratch (pairs/blockbase/ccnt/cstart ~ 8MB) overlays A
    // (dead until k_gemm<NF>); t2 (0.8MB) also overlays A (dead after the
    // layer-1 k_seg consumes T1).
    float* A      = (float*)d_ws;
    float* Bb     = A + (long long)N * NH;
    float* dis    = Bb + (long long)N * NH;
    int*   cnt    = (int*)(dis + N);
    int*   start  = cnt + N;
    int*   esrc   = start + N;
    int*   fmt    = esrc + E;
    float2* t2    = (float2*)A;

    int* pairs     = (int*)A;                          // E ints (overlay A)
    int* blockbase = pairs + E;                        // A1G * NB
    int* ccnt      = blockbase + (long long)A1G * NB;  // NB*16 (line-padded)
    int* cstart    = ccnt + NB * 16;                   // NB

    int nb_n  = (N + 255) / 256;
    int nb_g  = (N + 63) / 64;
    int nb_s  = (N + 3) / 4;
    int nb_i0 = (NB * 16 + 255) / 256;

    // per-call two-level bucket sort (inputs restored before every call)
    k_init0   <<<nb_i0, 256, 0, stream>>>(ei, fmt, ccnt, NB * 16);
    k_coarse  <<<A1G, 256, 0, stream>>>(ei, fmt, ccnt, blockbase, E, NB);
    k_cscan   <<<1, 512, 0, stream>>>(ccnt, cstart, NB);
    k_cscatter<<<A1G, 256, 0, stream>>>(ei, fmt, cstart, blockbase, pairs, E, NB);
    k_bucket  <<<NB, 256, 0, stream>>>(pairs, ccnt, cstart, esrc, cnt, start, dis, N);

    // layer 0 (no activation)
    k_gemm<NF><<<nb_g, 256, 0, stream>>>(x, W0, dis, A, N);
    k_seg     <<<nb_s, 256, 0, stream>>>(A, esrc, start, cnt, dis, b0, Bb, N);

    // layer 1 (tanh deferred into k_gemm2's read)
    k_gemm<NH><<<nb_g, 256, 0, stream>>>(Bb, W1, dis, A, N);
    k_seg     <<<nb_s, 256, 0, stream>>>(A, esrc, start, cnt, dis, b1, Bb, N);

    // layer 2 (2-wide) + fused aggregation/head
    k_gemm2   <<<nb_n, 256, 0, stream>>>(Bb, W2, dis, t2, N);
    k_seg2f   <<<nb_n, 256, 0, stream>>>(t2, esrc, start, cnt, dis, b2, Wc, bc,
                                         out, emb, N);
}

// Round 12
// 378.150 us; speedup vs baseline: 1.1280x; 1.0185x over previous
//
#include <hip/hip_runtime.h>

// GCN forward: 3x GCNConv (128->64->64->2) + linear head (2->16).
// N=100000 nodes, E=1600000 edges (+self-loops handled analytically).
// Preprocessing: two-level LDS bucket sort (avoids the ~24G/s global
// returning-atomic wall). Aggregation: atomic-free FULL-WAVE segment-sum
// gathers (lane = channel) over int16 rows (128B = 2 lines vs fp32's 4)
// with PER-ROW scales fused into the transform GEMM.
// HISTORY NOTE: the half-wave/2-rows-per-load gather variant (rounds 7-9,11)
// produces ~3e-3 absmax REGARDLESS of dtype (even pure fp32) - structural
// bug never located; full-wave is the validated structure (2.44e-4 fp32).
// int16-rowwise quant error is provably <= rowmax/65534 ~ 3e-5/elem.
// dis[] pre-folded: T'[v]=dis[v]*t[v] => O[i]=dis[i]*(T'[i]+sum T'[s])+b.

#define NF 128
#define NH 64
#define NPB 256      // nodes per coarse bucket (bucket = dst >> 8)
#define MAXNB 512    // max coarse buckets (N < 131072, matches 17-bit src pack)
#define CAP 6144     // max edges per coarse bucket (mean 4096, >30 sigma)
#define A1G 1024     // grid for coarse count/scatter (must match between them)

// Zero coarse counters + detect int64 vs int32 edge_index layout.
__global__ void k_init0(const int* __restrict__ ei, int* __restrict__ fmt,
                        int* __restrict__ ccnt, int nb16) {
    int i = blockIdx.x * 256 + threadIdx.x;
    if (i < nb16) ccnt[i] = 0;
    if (i == 0) {
        int f = 1;
        #pragma unroll
        for (int k = 1; k < 32; k += 2) if (ei[k] != 0) f = 0;
        *fmt = f;   // 1 => int64 (stride 2 in int32 words), 0 => int32
    }
}

// Coarse count: LDS histogram per block, then reserve per-(block,bucket) space
// with ONE padded global atomic per bucket per block (line-parallel).
__global__ void __launch_bounds__(256) k_coarse(
        const int* __restrict__ ei, const int* __restrict__ fmt,
        int* __restrict__ ccnt, int* __restrict__ blockbase, int E, int NB) {
    __shared__ int h[MAXNB];
    int sh = *fmt;
    for (int i = threadIdx.x; i < NB; i += 256) h[i] = 0;
    __syncthreads();
    for (long long e = (long long)blockIdx.x * 256 + threadIdx.x; e < E;
         e += (long long)A1G * 256) {
        int d = ei[(long long)(E + e) << sh];
        atomicAdd(&h[d >> 8], 1);
    }
    __syncthreads();
    for (int b = threadIdx.x; b < NB; b += 256) {
        int c = h[b];
        int base = (c > 0) ? atomicAdd(&ccnt[b * 16], c) : 0;
        blockbase[(long long)blockIdx.x * NB + b] = base;
    }
}

// Exclusive scan of the NB coarse counts (single block).
__global__ void __launch_bounds__(512) k_cscan(
        const int* __restrict__ ccnt, int* __restrict__ cstart, int NB) {
    __shared__ int s[512];
    int t = threadIdx.x;
    int c = (t < NB) ? ccnt[t * 16] : 0;
    s[t] = c;
    __syncthreads();
    for (int off = 1; off < 512; off <<= 1) {
        int v = s[t];
        int u = (t >= off) ? s[t - off] : 0;
        __syncthreads();
        s[t] = v + u;
        __syncthreads();
    }
    if (t < NB) cstart[t] = s[t] - c;
}

// Coarse scatter: same grid-stride partition as k_coarse, so this block's
// per-bucket totals equal its reservation. Per-bucket write bases staged in
// LDS once. Local ranks via LDS atomics. Edge packed as src | (dst&255)<<17.
__global__ void __launch_bounds__(256) k_cscatter(
        const int* __restrict__ ei, const int* __restrict__ fmt,
        const int* __restrict__ cstart, const int* __restrict__ blockbase,
        int* __restrict__ pairs, int E, int NB) {
    __shared__ int h[MAXNB];
    __shared__ int bb[MAXNB];
    int sh = *fmt;
    for (int i = threadIdx.x; i < NB; i += 256) {
        h[i] = 0;
        bb[i] = cstart[i] + blockbase[(long long)blockIdx.x * NB + i];
    }
    __syncthreads();
    for (long long e = (long long)blockIdx.x * 256 + threadIdx.x; e < E;
         e += (long long)A1G * 256) {
        int s = ei[(long long)e << sh];
        int d = ei[(long long)(E + e) << sh];
        int b = d >> 8;
        int r = atomicAdd(&h[b], 1);
        pairs[bb[b] + r] = s | ((d & 255) << 17);
    }
}

// Fine sort: one block per coarse bucket, entirely in LDS. Emits cnt/start/dis
// (coalesced) and esrc (scatter within the bucket's contiguous window).
__global__ void __launch_bounds__(256) k_bucket(
        const int* __restrict__ pairs, const int* __restrict__ ccnt,
        const int* __restrict__ cstart, int* __restrict__ esrc,
        int* __restrict__ cnt, int* __restrict__ start, float* __restrict__ dis,
        int N) {
    __shared__ int words[CAP];
    __shared__ unsigned char rk[CAP];
    __shared__ int h[NPB];
    __shared__ int hs[NPB];
    int b = blockIdx.x;
    int cs = cstart[b];
    int ec = ccnt[b * 16];
    if (ec > CAP) ec = CAP;          // memory-safety clamp (P ~ 0 for uniform dst)
    int t = threadIdx.x;
    for (int i = t; i < ec; i += 256) words[i] = pairs[cs + i];
    h[t] = 0;
    __syncthreads();
    for (int i = t; i < ec; i += 256) {
        int ld = words[i] >> 17;
        rk[i] = (unsigned char)atomicAdd(&h[ld], 1);
    }
    __syncthreads();
    int c = h[t];
    hs[t] = c;
    __syncthreads();
    for (int off = 1; off < 256; off <<= 1) {
        int v = hs[t];
        int u = (t >= off) ? hs[t - off] : 0;
        __syncthreads();
        hs[t] = v + u;               // inclusive scan
        __syncthreads();
    }
    int node = b * NPB + t;
    if (node < N) {
        cnt[node] = c;
        start[node] = cs + hs[t] - c;
        dis[node] = rsqrtf(1.0f + (float)c);   // degree includes self-loop
    }
    for (int i = t; i < ec; i += 256) {
        int w = words[i];
        int ld = w >> 17;
        esrc[cs + (hs[ld] - h[ld]) + rk[i]] = w & 0x1FFFF;
    }
}

// T16[n,NH] (int16) = quant_rowwise( dis[n] * (X[n,K] @ W[K,NH]) );
// rs[n] = rowmax/32767. 64 rows/block, 4x4 per thread; per-row max via LDS
// atomicMax across the 16 threads sharing a row (abs values: int cmp valid).
template<int K>
__global__ void __launch_bounds__(256) k_gemm(
        const float* __restrict__ X, const float* __restrict__ W,
        const float* __restrict__ dis, short* __restrict__ T16,
        float* __restrict__ rs, int n) {
    constexpr int KP = K + 4;
    __shared__ float xs[64 * KP];
    __shared__ float Ws[K * NH];
    __shared__ int rmax[64];
    if (threadIdx.x < 64) rmax[threadIdx.x] = 0;
    for (int i = threadIdx.x; i < K * NH / 4; i += 256)
        ((float4*)Ws)[i] = ((const float4*)W)[i];
    long long rowbase = (long long)blockIdx.x * 64;
    const float4* X4 = (const float4*)(X + rowbase * K);
    long long lim4 = ((long long)n * K - rowbase * K) >> 2;  // remaining float4s
    for (int i = threadIdx.x; i < 16 * K; i += 256) {
        float4 v = (i < lim4) ? X4[i] : make_float4(0.f, 0.f, 0.f, 0.f);
        int r = i / (K / 4), kk = (i % (K / 4)) * 4;
        *(float4*)&xs[r * KP + kk] = v;
    }
    __syncthreads();
    int c0 = (threadIdx.x & 15) * 4;
    int r0 = (threadIdx.x >> 4) * 4;
    const float* x0 = &xs[(r0 + 0) * KP];
    const float* x1 = &xs[(r0 + 1) * KP];
    const float* x2 = &xs[(r0 + 2) * KP];
    const float* x3 = &xs[(r0 + 3) * KP];
    float4 a0{0,0,0,0}, a1{0,0,0,0}, a2{0,0,0,0}, a3{0,0,0,0};
    #pragma unroll 4
    for (int k = 0; k < K; ++k) {
        float4 w = *(const float4*)&Ws[k * NH + c0];
        float v0 = x0[k], v1 = x1[k], v2 = x2[k], v3 = x3[k];
        a0.x += v0 * w.x; a0.y += v0 * w.y; a0.z += v0 * w.z; a0.w += v0 * w.w;
        a1.x += v1 * w.x; a1.y += v1 * w.y; a1.z += v1 * w.z; a1.w += v1 * w.w;
        a2.x += v2 * w.x; a2.y += v2 * w.y; a2.z += v2 * w.z; a2.w += v2 * w.w;
        a3.x += v3 * w.x; a3.y += v3 * w.y; a3.z += v3 * w.z; a3.w += v3 * w.w;
    }
    int row = (int)rowbase + r0;
    float d0 = (row + 0 < n) ? dis[row + 0] : 0.0f;
    float d1 = (row + 1 < n) ? dis[row + 1] : 0.0f;
    float d2 = (row + 2 < n) ? dis[row + 2] : 0.0f;
    float d3 = (row + 3 < n) ? dis[row + 3] : 0.0f;
    a0.x *= d0; a0.y *= d0; a0.z *= d0; a0.w *= d0;
    a1.x *= d1; a1.y *= d1; a1.z *= d1; a1.w *= d1;
    a2.x *= d2; a2.y *= d2; a2.z *= d2; a2.w *= d2;
    a3.x *= d3; a3.y *= d3; a3.z *= d3; a3.w *= d3;
    float m0 = fmaxf(fmaxf(fabsf(a0.x), fabsf(a0.y)), fmaxf(fabsf(a0.z), fabsf(a0.w)));
    float m1 = fmaxf(fmaxf(fabsf(a1.x), fabsf(a1.y)), fmaxf(fabsf(a1.z), fabsf(a1.w)));
    float m2 = fmaxf(fmaxf(fabsf(a2.x), fabsf(a2.y)), fmaxf(fabsf(a2.z), fabsf(a2.w)));
    float m3 = fmaxf(fmaxf(fabsf(a3.x), fabsf(a3.y)), fmaxf(fabsf(a3.z), fabsf(a3.w)));
    atomicMax(&rmax[r0 + 0], __float_as_int(m0));
    atomicMax(&rmax[r0 + 1], __float_as_int(m1));
    atomicMax(&rmax[r0 + 2], __float_as_int(m2));
    atomicMax(&rmax[r0 + 3], __float_as_int(m3));
    __syncthreads();
    float M0 = __int_as_float(rmax[r0 + 0]);
    float M1 = __int_as_float(rmax[r0 + 1]);
    float M2 = __int_as_float(rmax[r0 + 2]);
    float M3 = __int_as_float(rmax[r0 + 3]);
    float i0 = 32767.0f / fmaxf(M0, 1e-20f);
    float i1 = 32767.0f / fmaxf(M1, 1e-20f);
    float i2 = 32767.0f / fmaxf(M2, 1e-20f);
    float i3 = 32767.0f / fmaxf(M3, 1e-20f);
    const float ks = 1.0f / 32767.0f;
    if (row + 0 < n) {
        short4 q = { (short)__float2int_rn(a0.x * i0), (short)__float2int_rn(a0.y * i0),
                     (short)__float2int_rn(a0.z * i0), (short)__float2int_rn(a0.w * i0) };
        *(short4*)&T16[(long long)(row + 0) * NH + c0] = q;
        if (c0 == 0) rs[row + 0] = M0 * ks;
    }
    if (row + 1 < n) {
        short4 q = { (short)__float2int_rn(a1.x * i1), (short)__float2int_rn(a1.y * i1),
                     (short)__float2int_rn(a1.z * i1), (short)__float2int_rn(a1.w * i1) };
        *(short4*)&T16[(long long)(row + 1) * NH + c0] = q;
        if (c0 == 0) rs[row + 1] = M1 * ks;
    }
    if (row + 2 < n) {
        short4 q = { (short)__float2int_rn(a2.x * i2), (short)__float2int_rn(a2.y * i2),
                     (short)__float2int_rn(a2.z * i2), (short)__float2int_rn(a2.w * i2) };
        *(short4*)&T16[(long long)(row + 2) * NH + c0] = q;
        if (c0 == 0) rs[row + 2] = M2 * ks;
    }
    if (row + 3 < n) {
        short4 q = { (short)__float2int_rn(a3.x * i3), (short)__float2int_rn(a3.y * i3),
                     (short)__float2int_rn(a3.z * i3), (short)__float2int_rn(a3.w * i3) };
        *(short4*)&T16[(long long)(row + 3) * NH + c0] = q;
        if (c0 == 0) rs[row + 3] = M3 * ks;
    }
}

// O[i] = dis[i]*(rs[i]*Q[i] + sum_{s} rs[s]*Q[s]) + b   (FULL-WAVE: wave per
// node, lane = channel, 8-deep gather unroll). Identical structure to the
// validated fp32 k_seg; only the element load (short + rs fma) differs.
__global__ void __launch_bounds__(256) k_seg(
        const short* __restrict__ T, const float* __restrict__ rs,
        const int* __restrict__ esrc, const int* __restrict__ start,
        const int* __restrict__ cnt, const float* __restrict__ dis,
        const float* __restrict__ b, float* __restrict__ O, int n) {
    int lane = threadIdx.x & 63;
    int node = blockIdx.x * 4 + (threadIdx.x >> 6);
    if (node >= n) return;
    float di = dis[node];
    int g = cnt[node], st = start[node];
    float acc = rs[node] * (float)T[node * NH + lane];   // self-loop term
    for (int base = 0; base < g; base += 64) {
        int m = g - base; if (m > 64) m = 64;
        int sIdx = (lane < m) ? esrc[st + base + lane] : 0;
        int j = 0;
        for (; j + 7 < m; j += 8) {
            int s0 = __shfl(sIdx, j, 64),   s1 = __shfl(sIdx, j+1, 64);
            int s2 = __shfl(sIdx, j+2, 64), s3 = __shfl(sIdx, j+3, 64);
            int s4 = __shfl(sIdx, j+4, 64), s5 = __shfl(sIdx, j+5, 64);
            int s6 = __shfl(sIdx, j+6, 64), s7 = __shfl(sIdx, j+7, 64);
            float f0 = rs[s0], f1 = rs[s1], f2 = rs[s2], f3 = rs[s3];
            float f4 = rs[s4], f5 = rs[s5], f6 = rs[s6], f7 = rs[s7];
            short v0 = T[s0 * NH + lane];
            short v1 = T[s1 * NH + lane];
            short v2 = T[s2 * NH + lane];
            short v3 = T[s3 * NH + lane];
            short v4 = T[s4 * NH + lane];
            short v5 = T[s5 * NH + lane];
            short v6 = T[s6 * NH + lane];
            short v7 = T[s7 * NH + lane];
            acc = fmaf(f0, (float)v0, acc);
            acc = fmaf(f1, (float)v1, acc);
            acc = fmaf(f2, (float)v2, acc);
            acc = fmaf(f3, (float)v3, acc);
            acc = fmaf(f4, (float)v4, acc);
            acc = fmaf(f5, (float)v5, acc);
            acc = fmaf(f6, (float)v6, acc);
            acc = fmaf(f7, (float)v7, acc);
        }
        for (; j < m; ++j) {
            int s = __shfl(sIdx, j, 64);
            acc = fmaf(rs[s], (float)T[s * NH + lane], acc);
        }
    }
    O[(long long)node * NH + lane] = di * acc + b[lane];
}

// t2'[i] = dis[i] * (tanh(z1[i]) @ W2)  (64x2)
__global__ void __launch_bounds__(256) k_gemm2(
        const float* __restrict__ z1, const float* __restrict__ W2,
        const float* __restrict__ dis, float2* __restrict__ t2, int n) {
    __shared__ float Ws[NH * 2];
    if (threadIdx.x < NH * 2) Ws[threadIdx.x] = W2[threadIdx.x];
    __syncthreads();
    int i = blockIdx.x * 256 + threadIdx.x;
    if (i >= n) return;
    const float4* zr = (const float4*)(z1 + (long long)i * NH);
    float a0 = 0.0f, a1 = 0.0f;
    #pragma unroll
    for (int k4 = 0; k4 < NH / 4; ++k4) {
        float4 z = zr[k4];
        float t;
        t = tanhf(z.x); a0 += t * Ws[(k4*4+0)*2]; a1 += t * Ws[(k4*4+0)*2+1];
        t = tanhf(z.y); a0 += t * Ws[(k4*4+1)*2]; a1 += t * Ws[(k4*4+1)*2+1];
        t = tanhf(z.z); a0 += t * Ws[(k4*4+2)*2]; a1 += t * Ws[(k4*4+2)*2+1];
        t = tanhf(z.w); a0 += t * Ws[(k4*4+3)*2]; a1 += t * Ws[(k4*4+3)*2+1];
    }
    float di = dis[i];
    t2[i] = make_float2(a0 * di, a1 * di);
}

// Fused layer-2 aggregation + head: agg2 = di*(t2[i]+sum t2[s]) + b2;
// emb = tanh(agg2); out = emb @ Wc + bc.
__global__ void __launch_bounds__(256) k_seg2f(
        const float2* __restrict__ T2, const int* __restrict__ esrc,
        const int* __restrict__ start, const int* __restrict__ cnt,
        const float* __restrict__ dis, const float* __restrict__ b2,
        const float* __restrict__ Wc, const float* __restrict__ bc,
        float* __restrict__ out, float* __restrict__ emb, int n) {
    __shared__ float Wcs[32];
    __shared__ float bcs[16];
    if (threadIdx.x < 32) Wcs[threadIdx.x] = Wc[threadIdx.x];
    if (threadIdx.x < 16) bcs[threadIdx.x] = bc[threadIdx.x];
    __syncthreads();
    int i = blockIdx.x * 256 + threadIdx.x;
    if (i >= n) return;
    float di = dis[i];
    int g = cnt[i], st = start[i];
    float2 self = T2[i];
    float a0 = self.x, a1 = self.y;
    int j = 0;
    for (; j + 7 < g; j += 8) {
        int e0 = esrc[st+j],   e1 = esrc[st+j+1], e2 = esrc[st+j+2], e3 = esrc[st+j+3];
        int e4 = esrc[st+j+4], e5 = esrc[st+j+5], e6 = esrc[st+j+6], e7 = esrc[st+j+7];
        float2 v0 = T2[e0], v1 = T2[e1], v2 = T2[e2], v3 = T2[e3];
        float2 v4 = T2[e4], v5 = T2[e5], v6 = T2[e6], v7 = T2[e7];
        a0 += v0.x + v1.x + v2.x + v3.x + v4.x + v5.x + v6.x + v7.x;
        a1 += v0.y + v1.y + v2.y + v3.y + v4.y + v5.y + v6.y + v7.y;
    }
    for (; j < g; ++j) {
        float2 v = T2[esrc[st + j]];
        a0 += v.x; a1 += v.y;
    }
    float e0 = tanhf(a0 * di + b2[0]);
    float e1 = tanhf(a1 * di + b2[1]);
    *(float2*)&emb[(long long)i * 2] = make_float2(e0, e1);
    float* op = &out[(long long)i * 16];
    #pragma unroll
    for (int c4 = 0; c4 < 4; ++c4) {
        float4 o;
        o.x = e0 * Wcs[c4*4+0] + e1 * Wcs[16 + c4*4+0] + bcs[c4*4+0];
        o.y = e0 * Wcs[c4*4+1] + e1 * Wcs[16 + c4*4+1] + bcs[c4*4+1];
        o.z = e0 * Wcs[c4*4+2] + e1 * Wcs[16 + c4*4+2] + bcs[c4*4+2];
        o.w = e0 * Wcs[c4*4+3] + e1 * Wcs[16 + c4*4+3] + bcs[c4*4+3];
        *(float4*)&op[c4 * 4] = o;
    }
}

extern "C" void kernel_launch(void* const* d_in, const int* in_sizes, int n_in,
                              void* d_out, int out_size, void* d_ws, size_t ws_size,
                              hipStream_t stream) {
    const float* x  = (const float*)d_in[0];
    const int*   ei = (const int*)  d_in[1];
    const float* W0 = (const float*)d_in[2];
    const float* b0 = (const float*)d_in[3];
    const float* W1 = (const float*)d_in[4];
    const float* b1 = (const float*)d_in[5];
    const float* W2 = (const float*)d_in[6];
    const float* b2 = (const float*)d_in[7];
    const float* Wc = (const float*)d_in[8];
    const float* bc = (const float*)d_in[9];

    int N = in_sizes[0] / NF;
    int E = in_sizes[1] / 2;
    int NB = (N + NPB - 1) / NPB;   // 391 for N=100000 (must be <= MAXNB)

    float* out = (float*)d_out;                    // [N,16]
    float* emb = out + (long long)N * 16;          // [N,2]

    // workspace: T16[N*64 int16 = 12.8MB] | Bb[N*64 fp32] | dis[N] | rs[N] |
    //            cnt[N] | start[N] | esrc[E] | fmt
    // Preprocessing scratch (pairs/blockbase/ccnt/cstart ~ 8MB) overlays T16
    // (dead until the first k_gemm). t2 (0.8MB) also overlays T16 (dead after
    // the layer-1 k_seg consumes it; k_gemm2 reads Bb, writes t2 - no alias).
    short* T16    = (short*)d_ws;
    float* Bb     = (float*)((char*)d_ws + (long long)N * NH * 2);
    float* dis    = Bb + (long long)N * NH;
    float* rs     = dis + N;
    int*   cnt    = (int*)(rs + N);
    int*   start  = cnt + N;
    int*   esrc   = start + N;
    int*   fmt    = esrc + E;
    float2* t2    = (float2*)T16;

    int* pairs     = (int*)d_ws;                       // E ints (overlay T16)
    int* blockbase = pairs + E;                        // A1G * NB
    int* ccnt      = blockbase + (long long)A1G * NB;  // NB*16 (line-padded)
    int* cstart    = ccnt + NB * 16;                   // NB

    int nb_n  = (N + 255) / 256;
    int nb_g  = (N + 63) / 64;
    int nb_s  = (N + 3) / 4;
    int nb_i0 = (NB * 16 + 255) / 256;

    // per-call two-level bucket sort (inputs restored before every call)
    k_init0   <<<nb_i0, 256, 0, stream>>>(ei, fmt, ccnt, NB * 16);
    k_coarse  <<<A1G, 256, 0, stream>>>(ei, fmt, ccnt, blockbase, E, NB);
    k_cscan   <<<1, 512, 0, stream>>>(ccnt, cstart, NB);
    k_cscatter<<<A1G, 256, 0, stream>>>(ei, fmt, cstart, blockbase, pairs, E, NB);
    k_bucket  <<<NB, 256, 0, stream>>>(pairs, ccnt, cstart, esrc, cnt, start, dis, N);

    // layer 0 (no activation): fused gemm + rowwise int16 quant -> gather-sum
    k_gemm<NF><<<nb_g, 256, 0, stream>>>(x, W0, dis, T16, rs, N);
    k_seg     <<<nb_s, 256, 0, stream>>>(T16, rs, esrc, start, cnt, dis, b0, Bb, N);

    // layer 1 (tanh deferred into k_gemm2's read)
    k_gemm<NH><<<nb_g, 256, 0, stream>>>(Bb, W1, dis, T16, rs, N);
    k_seg     <<<nb_s, 256, 0, stream>>>(T16, rs, esrc, start, cnt, dis, b1, Bb, N);

    // layer 2 (2-wide) + fused aggregation/head
    k_gemm2   <<<nb_n, 256, 0, stream>>>(Bb, W2, dis, t2, N);
    k_seg2f   <<<nb_n, 256, 0, stream>>>(t2, esrc, start, cnt, dis, b2, Wc, bc,
                                         out, emb, N);
}

// Round 13
// 373.349 us; speedup vs baseline: 1.1425x; 1.0129x over previous
//
#include <hip/hip_runtime.h>

// GCN forward: 3x GCNConv (128->64->64->2) + linear head (2->16).
// N=100000 nodes, E=1600000 edges (+self-loops handled analytically).
// Preprocessing: two-level LDS bucket sort (avoids the ~24G/s global
// returning-atomic wall). Aggregation: atomic-free FULL-WAVE segment-sum
// gathers (lane = channel) over int16 rows (128B = 2 lines) with per-row
// scales fused into the transform GEMM. Edge indices are wave-uniform ->
// readlane into SGPRs (SALU address math, saddr loads, scalar rs loads).
// HISTORY: half-wave/2-rows-per-load gather gives ~3e-3 absmax regardless of
// dtype (even fp32) - structural bug, banned. Full-wave int16-rowwise
// validated at 4.88e-4 (threshold 2.66e-3).
// dis[] pre-folded: T'[v]=dis[v]*t[v] => O[i]=dis[i]*(T'[i]+sum T'[s])+b.
// Layer-2 transform (tanh @ W2) fused into layer-1 gather epilogue (k_seg1f);
// layer-2 aggregation + head fused (k_seg2f).

#define NF 128
#define NH 64
#define NPB 256      // nodes per coarse bucket (bucket = dst >> 8)
#define MAXNB 512    // max coarse buckets (N < 131072, matches 17-bit src pack)
#define CAP 6144     // max edges per coarse bucket (mean 4096, >30 sigma)
#define A1G 1024     // grid for coarse count/scatter (must match between them)

// Zero coarse counters + detect int64 vs int32 edge_index layout.
__global__ void k_init0(const int* __restrict__ ei, int* __restrict__ fmt,
                        int* __restrict__ ccnt, int nb16) {
    int i = blockIdx.x * 256 + threadIdx.x;
    if (i < nb16) ccnt[i] = 0;
    if (i == 0) {
        int f = 1;
        #pragma unroll
        for (int k = 1; k < 32; k += 2) if (ei[k] != 0) f = 0;
        *fmt = f;   // 1 => int64 (stride 2 in int32 words), 0 => int32
    }
}

// Coarse count: LDS histogram per block, then reserve per-(block,bucket) space
// with ONE padded global atomic per bucket per block (line-parallel).
__global__ void __launch_bounds__(256) k_coarse(
        const int* __restrict__ ei, const int* __restrict__ fmt,
        int* __restrict__ ccnt, int* __restrict__ blockbase, int E, int NB) {
    __shared__ int h[MAXNB];
    int sh = *fmt;
    for (int i = threadIdx.x; i < NB; i += 256) h[i] = 0;
    __syncthreads();
    for (long long e = (long long)blockIdx.x * 256 + threadIdx.x; e < E;
         e += (long long)A1G * 256) {
        int d = ei[(long long)(E + e) << sh];
        atomicAdd(&h[d >> 8], 1);
    }
    __syncthreads();
    for (int b = threadIdx.x; b < NB; b += 256) {
        int c = h[b];
        int base = (c > 0) ? atomicAdd(&ccnt[b * 16], c) : 0;
        blockbase[(long long)blockIdx.x * NB + b] = base;
    }
}

// Exclusive scan of the NB coarse counts (single block).
__global__ void __launch_bounds__(512) k_cscan(
        const int* __restrict__ ccnt, int* __restrict__ cstart, int NB) {
    __shared__ int s[512];
    int t = threadIdx.x;
    int c = (t < NB) ? ccnt[t * 16] : 0;
    s[t] = c;
    __syncthreads();
    for (int off = 1; off < 512; off <<= 1) {
        int v = s[t];
        int u = (t >= off) ? s[t - off] : 0;
        __syncthreads();
        s[t] = v + u;
        __syncthreads();
    }
    if (t < NB) cstart[t] = s[t] - c;
}

// Coarse scatter: same grid-stride partition as k_coarse, so this block's
// per-bucket totals equal its reservation. Per-bucket write bases staged in
// LDS once. Local ranks via LDS atomics. Edge packed as src | (dst&255)<<17.
__global__ void __launch_bounds__(256) k_cscatter(
        const int* __restrict__ ei, const int* __restrict__ fmt,
        const int* __restrict__ cstart, const int* __restrict__ blockbase,
        int* __restrict__ pairs, int E, int NB) {
    __shared__ int h[MAXNB];
    __shared__ int bb[MAXNB];
    int sh = *fmt;
    for (int i = threadIdx.x; i < NB; i += 256) {
        h[i] = 0;
        bb[i] = cstart[i] + blockbase[(long long)blockIdx.x * NB + i];
    }
    __syncthreads();
    for (long long e = (long long)blockIdx.x * 256 + threadIdx.x; e < E;
         e += (long long)A1G * 256) {
        int s = ei[(long long)e << sh];
        int d = ei[(long long)(E + e) << sh];
        int b = d >> 8;
        int r = atomicAdd(&h[b], 1);
        pairs[bb[b] + r] = s | ((d & 255) << 17);
    }
}

// Fine sort: one block per coarse bucket, entirely in LDS. Emits cnt/start/dis
// (coalesced) and esrc (scatter within the bucket's contiguous window).
__global__ void __launch_bounds__(256) k_bucket(
        const int* __restrict__ pairs, const int* __restrict__ ccnt,
        const int* __restrict__ cstart, int* __restrict__ esrc,
        int* __restrict__ cnt, int* __restrict__ start, float* __restrict__ dis,
        int N) {
    __shared__ int words[CAP];
    __shared__ unsigned char rk[CAP];
    __shared__ int h[NPB];
    __shared__ int hs[NPB];
    int b = blockIdx.x;
    int cs = cstart[b];
    int ec = ccnt[b * 16];
    if (ec > CAP) ec = CAP;          // memory-safety clamp (P ~ 0 for uniform dst)
    int t = threadIdx.x;
    for (int i = t; i < ec; i += 256) words[i] = pairs[cs + i];
    h[t] = 0;
    __syncthreads();
    for (int i = t; i < ec; i += 256) {
        int ld = words[i] >> 17;
        rk[i] = (unsigned char)atomicAdd(&h[ld], 1);
    }
    __syncthreads();
    int c = h[t];
    hs[t] = c;
    __syncthreads();
    for (int off = 1; off < 256; off <<= 1) {
        int v = hs[t];
        int u = (t >= off) ? hs[t - off] : 0;
        __syncthreads();
        hs[t] = v + u;               // inclusive scan
        __syncthreads();
    }
    int node = b * NPB + t;
    if (node < N) {
        cnt[node] = c;
        start[node] = cs + hs[t] - c;
        dis[node] = rsqrtf(1.0f + (float)c);   // degree includes self-loop
    }
    for (int i = t; i < ec; i += 256) {
        int w = words[i];
        int ld = w >> 17;
        esrc[cs + (hs[ld] - h[ld]) + rk[i]] = w & 0x1FFFF;
    }
}

// T16[n,NH] (int16) = quant_rowwise( dis[n] * (X[n,K] @ W[K,NH]) );
// rs[n] = rowmax/32767. 64 rows/block, 4x4 per thread; per-row max via LDS
// atomicMax across the 16 threads sharing a row (abs values: int cmp valid).
template<int K>
__global__ void __launch_bounds__(256) k_gemm(
        const float* __restrict__ X, const float* __restrict__ W,
        const float* __restrict__ dis, short* __restrict__ T16,
        float* __restrict__ rs, int n) {
    constexpr int KP = K + 4;
    __shared__ float xs[64 * KP];
    __shared__ float Ws[K * NH];
    __shared__ int rmax[64];
    if (threadIdx.x < 64) rmax[threadIdx.x] = 0;
    for (int i = threadIdx.x; i < K * NH / 4; i += 256)
        ((float4*)Ws)[i] = ((const float4*)W)[i];
    long long rowbase = (long long)blockIdx.x * 64;
    const float4* X4 = (const float4*)(X + rowbase * K);
    long long lim4 = ((long long)n * K - rowbase * K) >> 2;  // remaining float4s
    for (int i = threadIdx.x; i < 16 * K; i += 256) {
        float4 v = (i < lim4) ? X4[i] : make_float4(0.f, 0.f, 0.f, 0.f);
        int r = i / (K / 4), kk = (i % (K / 4)) * 4;
        *(float4*)&xs[r * KP + kk] = v;
    }
    __syncthreads();
    int c0 = (threadIdx.x & 15) * 4;
    int r0 = (threadIdx.x >> 4) * 4;
    const float* x0 = &xs[(r0 + 0) * KP];
    const float* x1 = &xs[(r0 + 1) * KP];
    const float* x2 = &xs[(r0 + 2) * KP];
    const float* x3 = &xs[(r0 + 3) * KP];
    float4 a0{0,0,0,0}, a1{0,0,0,0}, a2{0,0,0,0}, a3{0,0,0,0};
    #pragma unroll 4
    for (int k = 0; k < K; ++k) {
        float4 w = *(const float4*)&Ws[k * NH + c0];
        float v0 = x0[k], v1 = x1[k], v2 = x2[k], v3 = x3[k];
        a0.x += v0 * w.x; a0.y += v0 * w.y; a0.z += v0 * w.z; a0.w += v0 * w.w;
        a1.x += v1 * w.x; a1.y += v1 * w.y; a1.z += v1 * w.z; a1.w += v1 * w.w;
        a2.x += v2 * w.x; a2.y += v2 * w.y; a2.z += v2 * w.z; a2.w += v2 * w.w;
        a3.x += v3 * w.x; a3.y += v3 * w.y; a3.z += v3 * w.z; a3.w += v3 * w.w;
    }
    int row = (int)rowbase + r0;
    float d0 = (row + 0 < n) ? dis[row + 0] : 0.0f;
    float d1 = (row + 1 < n) ? dis[row + 1] : 0.0f;
    float d2 = (row + 2 < n) ? dis[row + 2] : 0.0f;
    float d3 = (row + 3 < n) ? dis[row + 3] : 0.0f;
    a0.x *= d0; a0.y *= d0; a0.z *= d0; a0.w *= d0;
    a1.x *= d1; a1.y *= d1; a1.z *= d1; a1.w *= d1;
    a2.x *= d2; a2.y *= d2; a2.z *= d2; a2.w *= d2;
    a3.x *= d3; a3.y *= d3; a3.z *= d3; a3.w *= d3;
    float m0 = fmaxf(fmaxf(fabsf(a0.x), fabsf(a0.y)), fmaxf(fabsf(a0.z), fabsf(a0.w)));
    float m1 = fmaxf(fmaxf(fabsf(a1.x), fabsf(a1.y)), fmaxf(fabsf(a1.z), fabsf(a1.w)));
    float m2 = fmaxf(fmaxf(fabsf(a2.x), fabsf(a2.y)), fmaxf(fabsf(a2.z), fabsf(a2.w)));
    float m3 = fmaxf(fmaxf(fabsf(a3.x), fabsf(a3.y)), fmaxf(fabsf(a3.z), fabsf(a3.w)));
    atomicMax(&rmax[r0 + 0], __float_as_int(m0));
    atomicMax(&rmax[r0 + 1], __float_as_int(m1));
    atomicMax(&rmax[r0 + 2], __float_as_int(m2));
    atomicMax(&rmax[r0 + 3], __float_as_int(m3));
    __syncthreads();
    float M0 = __int_as_float(rmax[r0 + 0]);
    float M1 = __int_as_float(rmax[r0 + 1]);
    float M2 = __int_as_float(rmax[r0 + 2]);
    float M3 = __int_as_float(rmax[r0 + 3]);
    float i0 = 32767.0f / fmaxf(M0, 1e-20f);
    float i1 = 32767.0f / fmaxf(M1, 1e-20f);
    float i2 = 32767.0f / fmaxf(M2, 1e-20f);
    float i3 = 32767.0f / fmaxf(M3, 1e-20f);
    const float ks = 1.0f / 32767.0f;
    if (row + 0 < n) {
        short4 q = { (short)__float2int_rn(a0.x * i0), (short)__float2int_rn(a0.y * i0),
                     (short)__float2int_rn(a0.z * i0), (short)__float2int_rn(a0.w * i0) };
        *(short4*)&T16[(long long)(row + 0) * NH + c0] = q;
        if (c0 == 0) rs[row + 0] = M0 * ks;
    }
    if (row + 1 < n) {
        short4 q = { (short)__float2int_rn(a1.x * i1), (short)__float2int_rn(a1.y * i1),
                     (short)__float2int_rn(a1.z * i1), (short)__float2int_rn(a1.w * i1) };
        *(short4*)&T16[(long long)(row + 1) * NH + c0] = q;
        if (c0 == 0) rs[row + 1] = M1 * ks;
    }
    if (row + 2 < n) {
        short4 q = { (short)__float2int_rn(a2.x * i2), (short)__float2int_rn(a2.y * i2),
                     (short)__float2int_rn(a2.z * i2), (short)__float2int_rn(a2.w * i2) };
        *(short4*)&T16[(long long)(row + 2) * NH + c0] = q;
        if (c0 == 0) rs[row + 2] = M2 * ks;
    }
    if (row + 3 < n) {
        short4 q = { (short)__float2int_rn(a3.x * i3), (short)__float2int_rn(a3.y * i3),
                     (short)__float2int_rn(a3.z * i3), (short)__float2int_rn(a3.w * i3) };
        *(short4*)&T16[(long long)(row + 3) * NH + c0] = q;
        if (c0 == 0) rs[row + 3] = M3 * ks;
    }
}

// Core full-wave gather: wave per node, lane = channel. Edge indices are
// wave-uniform -> readlane puts them in SGPRs: address math goes to SALU,
// T loads become saddr-form, rs loads become scalar loads.
#define SEG_GATHER                                                            \
    int lane = threadIdx.x & 63;                                              \
    int node = blockIdx.x * 4 + (threadIdx.x >> 6);                           \
    if (node >= n) return;                                                    \
    float di = dis[node];                                                     \
    int g = cnt[node], st = start[node];                                      \
    float acc = rs[node] * (float)T[node * NH + lane];                        \
    for (int base = 0; base < g; base += 64) {                                \
        int m = g - base; if (m > 64) m = 64;                                 \
        int sIdx = (lane < m) ? esrc[st + base + lane] : 0;                   \
        int j = 0;                                                            \
        for (; j + 7 < m; j += 8) {                                           \
            int s0 = __builtin_amdgcn_readlane(sIdx, j + 0);                  \
            int s1 = __builtin_amdgcn_readlane(sIdx, j + 1);                  \
            int s2 = __builtin_amdgcn_readlane(sIdx, j + 2);                  \
            int s3 = __builtin_amdgcn_readlane(sIdx, j + 3);                  \
            int s4 = __builtin_amdgcn_readlane(sIdx, j + 4);                  \
            int s5 = __builtin_amdgcn_readlane(sIdx, j + 5);                  \
            int s6 = __builtin_amdgcn_readlane(sIdx, j + 6);                  \
            int s7 = __builtin_amdgcn_readlane(sIdx, j + 7);                  \
            float f0 = rs[s0], f1 = rs[s1], f2 = rs[s2], f3 = rs[s3];         \
            float f4 = rs[s4], f5 = rs[s5], f6 = rs[s6], f7 = rs[s7];         \
            short v0 = (T + s0 * NH)[lane];                                   \
            short v1 = (T + s1 * NH)[lane];                                   \
            short v2 = (T + s2 * NH)[lane];                                   \
            short v3 = (T + s3 * NH)[lane];                                   \
            short v4 = (T + s4 * NH)[lane];                                   \
            short v5 = (T + s5 * NH)[lane];                                   \
            short v6 = (T + s6 * NH)[lane];                                   \
            short v7 = (T + s7 * NH)[lane];                                   \
            acc = fmaf(f0, (float)v0, acc);                                   \
            acc = fmaf(f1, (float)v1, acc);                                   \
            acc = fmaf(f2, (float)v2, acc);                                   \
            acc = fmaf(f3, (float)v3, acc);                                   \
            acc = fmaf(f4, (float)v4, acc);                                   \
            acc = fmaf(f5, (float)v5, acc);                                   \
            acc = fmaf(f6, (float)v6, acc);                                   \
            acc = fmaf(f7, (float)v7, acc);                                   \
        }                                                                     \
        for (; j < m; ++j) {                                                  \
            int s = __builtin_amdgcn_readlane(sIdx, j);                       \
            acc = fmaf(rs[s], (float)(T + s * NH)[lane], acc);                \
        }                                                                     \
    }

// Layer-0: O[i] = di*acc + b (full 64-channel row out).
__global__ void __launch_bounds__(256) k_seg(
        const short* __restrict__ T, const float* __restrict__ rs,
        const int* __restrict__ esrc, const int* __restrict__ start,
        const int* __restrict__ cnt, const float* __restrict__ dis,
        const float* __restrict__ b, float* __restrict__ O, int n) {
    SEG_GATHER
    O[(long long)node * NH + lane] = di * acc + b[lane];
}

// Layer-1 + fused layer-2 transform: z1[c] = di*acc + b1[c] (c = lane);
// t = tanh(z1); t2[i] = di * (t @ W2) via 6-step full-wave butterfly.
__global__ void __launch_bounds__(256) k_seg1f(
        const short* __restrict__ T, const float* __restrict__ rs,
        const int* __restrict__ esrc, const int* __restrict__ start,
        const int* __restrict__ cnt, const float* __restrict__ dis,
        const float* __restrict__ b1, const float* __restrict__ W2,
        float2* __restrict__ t2, int n) {
    SEG_GATHER
    float t = tanhf(di * acc + b1[lane]);
    float2 w = ((const float2*)W2)[lane];   // W2[lane][0], W2[lane][1]
    float p0 = t * w.x;
    float p1 = t * w.y;
    #pragma unroll
    for (int msk = 32; msk; msk >>= 1) {
        p0 += __shfl_xor(p0, msk, 64);
        p1 += __shfl_xor(p1, msk, 64);
    }
    if (lane == 0) t2[node] = make_float2(di * p0, di * p1);
}

// Fused layer-2 aggregation + head: agg2 = di*(t2[i]+sum t2[s]) + b2;
// emb = tanh(agg2); out = emb @ Wc + bc.
__global__ void __launch_bounds__(256) k_seg2f(
        const float2* __restrict__ T2, const int* __restrict__ esrc,
        const int* __restrict__ start, const int* __restrict__ cnt,
        const float* __restrict__ dis, const float* __restrict__ b2,
        const float* __restrict__ Wc, const float* __restrict__ bc,
        float* __restrict__ out, float* __restrict__ emb, int n) {
    __shared__ float Wcs[32];
    __shared__ float bcs[16];
    if (threadIdx.x < 32) Wcs[threadIdx.x] = Wc[threadIdx.x];
    if (threadIdx.x < 16) bcs[threadIdx.x] = bc[threadIdx.x];
    __syncthreads();
    int i = blockIdx.x * 256 + threadIdx.x;
    if (i >= n) return;
    float di = dis[i];
    int g = cnt[i], st = start[i];
    float2 self = T2[i];
    float a0 = self.x, a1 = self.y;
    int j = 0;
    for (; j + 7 < g; j += 8) {
        int e0 = esrc[st+j],   e1 = esrc[st+j+1], e2 = esrc[st+j+2], e3 = esrc[st+j+3];
        int e4 = esrc[st+j+4], e5 = esrc[st+j+5], e6 = esrc[st+j+6], e7 = esrc[st+j+7];
        float2 v0 = T2[e0], v1 = T2[e1], v2 = T2[e2], v3 = T2[e3];
        float2 v4 = T2[e4], v5 = T2[e5], v6 = T2[e6], v7 = T2[e7];
        a0 += v0.x + v1.x + v2.x + v3.x + v4.x + v5.x + v6.x + v7.x;
        a1 += v0.y + v1.y + v2.y + v3.y + v4.y + v5.y + v6.y + v7.y;
    }
    for (; j < g; ++j) {
        float2 v = T2[esrc[st + j]];
        a0 += v.x; a1 += v.y;
    }
    float e0 = tanhf(a0 * di + b2[0]);
    float e1 = tanhf(a1 * di + b2[1]);
    *(float2*)&emb[(long long)i * 2] = make_float2(e0, e1);
    float* op = &out[(long long)i * 16];
    #pragma unroll
    for (int c4 = 0; c4 < 4; ++c4) {
        float4 o;
        o.x = e0 * Wcs[c4*4+0] + e1 * Wcs[16 + c4*4+0] + bcs[c4*4+0];
        o.y = e0 * Wcs[c4*4+1] + e1 * Wcs[16 + c4*4+1] + bcs[c4*4+1];
        o.z = e0 * Wcs[c4*4+2] + e1 * Wcs[16 + c4*4+2] + bcs[c4*4+2];
        o.w = e0 * Wcs[c4*4+3] + e1 * Wcs[16 + c4*4+3] + bcs[c4*4+3];
        *(float4*)&op[c4 * 4] = o;
    }
}

extern "C" void kernel_launch(void* const* d_in, const int* in_sizes, int n_in,
                              void* d_out, int out_size, void* d_ws, size_t ws_size,
                              hipStream_t stream) {
    const float* x  = (const float*)d_in[0];
    const int*   ei = (const int*)  d_in[1];
    const float* W0 = (const float*)d_in[2];
    const float* b0 = (const float*)d_in[3];
    const float* W1 = (const float*)d_in[4];
    const float* b1 = (const float*)d_in[5];
    const float* W2 = (const float*)d_in[6];
    const float* b2 = (const float*)d_in[7];
    const float* Wc = (const float*)d_in[8];
    const float* bc = (const float*)d_in[9];

    int N = in_sizes[0] / NF;
    int E = in_sizes[1] / 2;
    int NB = (N + NPB - 1) / NPB;   // 391 for N=100000 (must be <= MAXNB)

    float* out = (float*)d_out;                    // [N,16]
    float* emb = out + (long long)N * 16;          // [N,2]

    // workspace: T16[N*64 int16 = 12.8MB] | Bb[N*64 fp32] | dis[N] | rs[N] |
    //            cnt[N] | start[N] | esrc[E] | fmt
    // Preprocessing scratch (pairs/blockbase/ccnt/cstart ~ 8MB) overlays T16
    // (dead until the first k_gemm). t2 (0.8MB) lives at the start of Bb
    // (Bb dead after k_gemm<NH> consumes it; k_seg1f reads T16, writes t2).
    short* T16    = (short*)d_ws;
    float* Bb     = (float*)((char*)d_ws + (long long)N * NH * 2);
    float* dis    = Bb + (long long)N * NH;
    float* rs     = dis + N;
    int*   cnt    = (int*)(rs + N);
    int*   start  = cnt + N;
    int*   esrc   = start + N;
    int*   fmt    = esrc + E;
    float2* t2    = (float2*)Bb;

    int* pairs     = (int*)d_ws;                       // E ints (overlay T16)
    int* blockbase = pairs + E;                        // A1G * NB
    int* ccnt      = blockbase + (long long)A1G * NB;  // NB*16 (line-padded)
    int* cstart    = ccnt + NB * 16;                   // NB

    int nb_n  = (N + 255) / 256;
    int nb_g  = (N + 63) / 64;
    int nb_s  = (N + 3) / 4;
    int nb_i0 = (NB * 16 + 255) / 256;

    // per-call two-level bucket sort (inputs restored before every call)
    k_init0   <<<nb_i0, 256, 0, stream>>>(ei, fmt, ccnt, NB * 16);
    k_coarse  <<<A1G, 256, 0, stream>>>(ei, fmt, ccnt, blockbase, E, NB);
    k_cscan   <<<1, 512, 0, stream>>>(ccnt, cstart, NB);
    k_cscatter<<<A1G, 256, 0, stream>>>(ei, fmt, cstart, blockbase, pairs, E, NB);
    k_bucket  <<<NB, 256, 0, stream>>>(pairs, ccnt, cstart, esrc, cnt, start, dis, N);

    // layer 0 (no activation): fused gemm + rowwise int16 quant -> gather-sum
    k_gemm<NF><<<nb_g, 256, 0, stream>>>(x, W0, dis, T16, rs, N);
    k_seg     <<<nb_s, 256, 0, stream>>>(T16, rs, esrc, start, cnt, dis, b0, Bb, N);

    // layer 1 + fused layer-2 transform (tanh + @W2 in gather epilogue)
    k_gemm<NH><<<nb_g, 256, 0, stream>>>(Bb, W1, dis, T16, rs, N);
    k_seg1f   <<<nb_s, 256, 0, stream>>>(T16, rs, esrc, start, cnt, dis, b1, W2,
                                         t2, N);

    // layer-2 aggregation + head
    k_seg2f   <<<nb_n, 256, 0, stream>>>(t2, esrc, start, cnt, dis, b2, Wc, bc,
                                         out, emb, N);
}

// Round 14
// 364.279 us; speedup vs baseline: 1.1709x; 1.0249x over previous
//
#include <hip/hip_runtime.h>

// GCN forward: 3x GCNConv (128->64->64->2) + linear head (2->16).
// N=100000 nodes, E=1600000 edges (+self-loops handled analytically).
// Preprocessing: two-level LDS bucket sort (avoids the ~24G/s global
// returning-atomic wall). Aggregation: atomic-free FULL-WAVE segment-sum
// gathers (lane = channel) over int16 rows (128B = 2 lines) with per-row
// scales fused into the transform GEMM. Edge indices readlane'd into SGPRs
// (SALU address math + saddr T-loads); per-row SCALES are vector-gathered
// once per 64-edge batch and broadcast via readlane on the float bits --
// round 13 showed SGPR-indexed rs[] compiles to s_load and thrashes the
// scalar cache (62->71us regression).
// HISTORY: half-wave/2-rows-per-load gather gives ~3e-3 absmax regardless of
// dtype (even fp32) - structural bug, banned. Full-wave int16-rowwise
// validated at 4.88e-4 (threshold 2.66e-3).
// dis[] pre-folded: T'[v]=dis[v]*t[v] => O[i]=dis[i]*(T'[i]+sum T'[s])+b.
// Layer-2 transform (tanh @ W2) fused into layer-1 gather epilogue (k_seg1f);
// layer-2 aggregation + head fused (k_seg2f).

#define NF 128
#define NH 64
#define NPB 256      // nodes per coarse bucket (bucket = dst >> 8)
#define MAXNB 512    // max coarse buckets (N < 131072, matches 17-bit src pack)
#define CAP 6144     // max edges per coarse bucket (mean 4096, >30 sigma)
#define A1G 1024     // grid for coarse count/scatter (must match between them)

// Zero coarse counters + detect int64 vs int32 edge_index layout.
__global__ void k_init0(const int* __restrict__ ei, int* __restrict__ fmt,
                        int* __restrict__ ccnt, int nb16) {
    int i = blockIdx.x * 256 + threadIdx.x;
    if (i < nb16) ccnt[i] = 0;
    if (i == 0) {
        int f = 1;
        #pragma unroll
        for (int k = 1; k < 32; k += 2) if (ei[k] != 0) f = 0;
        *fmt = f;   // 1 => int64 (stride 2 in int32 words), 0 => int32
    }
}

// Coarse count: LDS histogram per block, then reserve per-(block,bucket) space
// with ONE padded global atomic per bucket per block (line-parallel).
__global__ void __launch_bounds__(256) k_coarse(
        const int* __restrict__ ei, const int* __restrict__ fmt,
        int* __restrict__ ccnt, int* __restrict__ blockbase, int E, int NB) {
    __shared__ int h[MAXNB];
    int sh = *fmt;
    for (int i = threadIdx.x; i < NB; i += 256) h[i] = 0;
    __syncthreads();
    for (long long e = (long long)blockIdx.x * 256 + threadIdx.x; e < E;
         e += (long long)A1G * 256) {
        int d = ei[(long long)(E + e) << sh];
        atomicAdd(&h[d >> 8], 1);
    }
    __syncthreads();
    for (int b = threadIdx.x; b < NB; b += 256) {
        int c = h[b];
        int base = (c > 0) ? atomicAdd(&ccnt[b * 16], c) : 0;
        blockbase[(long long)blockIdx.x * NB + b] = base;
    }
}

// Exclusive scan of the NB coarse counts (single block).
__global__ void __launch_bounds__(512) k_cscan(
        const int* __restrict__ ccnt, int* __restrict__ cstart, int NB) {
    __shared__ int s[512];
    int t = threadIdx.x;
    int c = (t < NB) ? ccnt[t * 16] : 0;
    s[t] = c;
    __syncthreads();
    for (int off = 1; off < 512; off <<= 1) {
        int v = s[t];
        int u = (t >= off) ? s[t - off] : 0;
        __syncthreads();
        s[t] = v + u;
        __syncthreads();
    }
    if (t < NB) cstart[t] = s[t] - c;
}

// Coarse scatter: same grid-stride partition as k_coarse, so this block's
// per-bucket totals equal its reservation. Per-bucket write bases staged in
// LDS once. Local ranks via LDS atomics. Edge packed as src | (dst&255)<<17.
__global__ void __launch_bounds__(256) k_cscatter(
        const int* __restrict__ ei, const int* __restrict__ fmt,
        const int* __restrict__ cstart, const int* __restrict__ blockbase,
        int* __restrict__ pairs, int E, int NB) {
    __shared__ int h[MAXNB];
    __shared__ int bb[MAXNB];
    int sh = *fmt;
    for (int i = threadIdx.x; i < NB; i += 256) {
        h[i] = 0;
        bb[i] = cstart[i] + blockbase[(long long)blockIdx.x * NB + i];
    }
    __syncthreads();
    for (long long e = (long long)blockIdx.x * 256 + threadIdx.x; e < E;
         e += (long long)A1G * 256) {
        int s = ei[(long long)e << sh];
        int d = ei[(long long)(E + e) << sh];
        int b = d >> 8;
        int r = atomicAdd(&h[b], 1);
        pairs[bb[b] + r] = s | ((d & 255) << 17);
    }
}

// Fine sort: one block per coarse bucket, entirely in LDS. Emits cnt/start/dis
// (coalesced) and esrc (scatter within the bucket's contiguous window).
__global__ void __launch_bounds__(256) k_bucket(
        const int* __restrict__ pairs, const int* __restrict__ ccnt,
        const int* __restrict__ cstart, int* __restrict__ esrc,
        int* __restrict__ cnt, int* __restrict__ start, float* __restrict__ dis,
        int N) {
    __shared__ int words[CAP];
    __shared__ unsigned char rk[CAP];
    __shared__ int h[NPB];
    __shared__ int hs[NPB];
    int b = blockIdx.x;
    int cs = cstart[b];
    int ec = ccnt[b * 16];
    if (ec > CAP) ec = CAP;          // memory-safety clamp (P ~ 0 for uniform dst)
    int t = threadIdx.x;
    for (int i = t; i < ec; i += 256) words[i] = pairs[cs + i];
    h[t] = 0;
    __syncthreads();
    for (int i = t; i < ec; i += 256) {
        int ld = words[i] >> 17;
        rk[i] = (unsigned char)atomicAdd(&h[ld], 1);
    }
    __syncthreads();
    int c = h[t];
    hs[t] = c;
    __syncthreads();
    for (int off = 1; off < 256; off <<= 1) {
        int v = hs[t];
        int u = (t >= off) ? hs[t - off] : 0;
        __syncthreads();
        hs[t] = v + u;               // inclusive scan
        __syncthreads();
    }
    int node = b * NPB + t;
    if (node < N) {
        cnt[node] = c;
        start[node] = cs + hs[t] - c;
        dis[node] = rsqrtf(1.0f + (float)c);   // degree includes self-loop
    }
    for (int i = t; i < ec; i += 256) {
        int w = words[i];
        int ld = w >> 17;
        esrc[cs + (hs[ld] - h[ld]) + rk[i]] = w & 0x1FFFF;
    }
}

// T16[n,NH] (int16) = quant_rowwise( dis[n] * (X[n,K] @ W[K,NH]) );
// rs[n] = rowmax/32767. 64 rows/block, 4x4 per thread; per-row max via LDS
// atomicMax across the 16 threads sharing a row (abs values: int cmp valid).
template<int K>
__global__ void __launch_bounds__(256) k_gemm(
        const float* __restrict__ X, const float* __restrict__ W,
        const float* __restrict__ dis, short* __restrict__ T16,
        float* __restrict__ rs, int n) {
    constexpr int KP = K + 4;
    __shared__ float xs[64 * KP];
    __shared__ float Ws[K * NH];
    __shared__ int rmax[64];
    if (threadIdx.x < 64) rmax[threadIdx.x] = 0;
    for (int i = threadIdx.x; i < K * NH / 4; i += 256)
        ((float4*)Ws)[i] = ((const float4*)W)[i];
    long long rowbase = (long long)blockIdx.x * 64;
    const float4* X4 = (const float4*)(X + rowbase * K);
    long long lim4 = ((long long)n * K - rowbase * K) >> 2;  // remaining float4s
    for (int i = threadIdx.x; i < 16 * K; i += 256) {
        float4 v = (i < lim4) ? X4[i] : make_float4(0.f, 0.f, 0.f, 0.f);
        int r = i / (K / 4), kk = (i % (K / 4)) * 4;
        *(float4*)&xs[r * KP + kk] = v;
    }
    __syncthreads();
    int c0 = (threadIdx.x & 15) * 4;
    int r0 = (threadIdx.x >> 4) * 4;
    const float* x0 = &xs[(r0 + 0) * KP];
    const float* x1 = &xs[(r0 + 1) * KP];
    const float* x2 = &xs[(r0 + 2) * KP];
    const float* x3 = &xs[(r0 + 3) * KP];
    float4 a0{0,0,0,0}, a1{0,0,0,0}, a2{0,0,0,0}, a3{0,0,0,0};
    #pragma unroll 4
    for (int k = 0; k < K; ++k) {
        float4 w = *(const float4*)&Ws[k * NH + c0];
        float v0 = x0[k], v1 = x1[k], v2 = x2[k], v3 = x3[k];
        a0.x += v0 * w.x; a0.y += v0 * w.y; a0.z += v0 * w.z; a0.w += v0 * w.w;
        a1.x += v1 * w.x; a1.y += v1 * w.y; a1.z += v1 * w.z; a1.w += v1 * w.w;
        a2.x += v2 * w.x; a2.y += v2 * w.y; a2.z += v2 * w.z; a2.w += v2 * w.w;
        a3.x += v3 * w.x; a3.y += v3 * w.y; a3.z += v3 * w.z; a3.w += v3 * w.w;
    }
    int row = (int)rowbase + r0;
    float d0 = (row + 0 < n) ? dis[row + 0] : 0.0f;
    float d1 = (row + 1 < n) ? dis[row + 1] : 0.0f;
    float d2 = (row + 2 < n) ? dis[row + 2] : 0.0f;
    float d3 = (row + 3 < n) ? dis[row + 3] : 0.0f;
    a0.x *= d0; a0.y *= d0; a0.z *= d0; a0.w *= d0;
    a1.x *= d1; a1.y *= d1; a1.z *= d1; a1.w *= d1;
    a2.x *= d2; a2.y *= d2; a2.z *= d2; a2.w *= d2;
    a3.x *= d3; a3.y *= d3; a3.z *= d3; a3.w *= d3;
    float m0 = fmaxf(fmaxf(fabsf(a0.x), fabsf(a0.y)), fmaxf(fabsf(a0.z), fabsf(a0.w)));
    float m1 = fmaxf(fmaxf(fabsf(a1.x), fabsf(a1.y)), fmaxf(fabsf(a1.z), fabsf(a1.w)));
    float m2 = fmaxf(fmaxf(fabsf(a2.x), fabsf(a2.y)), fmaxf(fabsf(a2.z), fabsf(a2.w)));
    float m3 = fmaxf(fmaxf(fabsf(a3.x), fabsf(a3.y)), fmaxf(fabsf(a3.z), fabsf(a3.w)));
    atomicMax(&rmax[r0 + 0], __float_as_int(m0));
    atomicMax(&rmax[r0 + 1], __float_as_int(m1));
    atomicMax(&rmax[r0 + 2], __float_as_int(m2));
    atomicMax(&rmax[r0 + 3], __float_as_int(m3));
    __syncthreads();
    float M0 = __int_as_float(rmax[r0 + 0]);
    float M1 = __int_as_float(rmax[r0 + 1]);
    float M2 = __int_as_float(rmax[r0 + 2]);
    float M3 = __int_as_float(rmax[r0 + 3]);
    float i0 = 32767.0f / fmaxf(M0, 1e-20f);
    float i1 = 32767.0f / fmaxf(M1, 1e-20f);
    float i2 = 32767.0f / fmaxf(M2, 1e-20f);
    float i3 = 32767.0f / fmaxf(M3, 1e-20f);
    const float ks = 1.0f / 32767.0f;
    if (row + 0 < n) {
        short4 q = { (short)__float2int_rn(a0.x * i0), (short)__float2int_rn(a0.y * i0),
                     (short)__float2int_rn(a0.z * i0), (short)__float2int_rn(a0.w * i0) };
        *(short4*)&T16[(long long)(row + 0) * NH + c0] = q;
        if (c0 == 0) rs[row + 0] = M0 * ks;
    }
    if (row + 1 < n) {
        short4 q = { (short)__float2int_rn(a1.x * i1), (short)__float2int_rn(a1.y * i1),
                     (short)__float2int_rn(a1.z * i1), (short)__float2int_rn(a1.w * i1) };
        *(short4*)&T16[(long long)(row + 1) * NH + c0] = q;
        if (c0 == 0) rs[row + 1] = M1 * ks;
    }
    if (row + 2 < n) {
        short4 q = { (short)__float2int_rn(a2.x * i2), (short)__float2int_rn(a2.y * i2),
                     (short)__float2int_rn(a2.z * i2), (short)__float2int_rn(a2.w * i2) };
        *(short4*)&T16[(long long)(row + 2) * NH + c0] = q;
        if (c0 == 0) rs[row + 2] = M2 * ks;
    }
    if (row + 3 < n) {
        short4 q = { (short)__float2int_rn(a3.x * i3), (short)__float2int_rn(a3.y * i3),
                     (short)__float2int_rn(a3.z * i3), (short)__float2int_rn(a3.w * i3) };
        *(short4*)&T16[(long long)(row + 3) * NH + c0] = q;
        if (c0 == 0) rs[row + 3] = M3 * ks;
    }
}

// Core full-wave gather: wave per node, lane = channel.
// sIdx (edge indices) AND fv (per-row scales) are vector-gathered once per
// 64-edge batch; per-edge values are broadcast via readlane (s -> SGPR for
// SALU/saddr T addressing, f -> readlane on float bits, NO scalar-mem loads).
#define SEG_GATHER                                                            \
    int lane = threadIdx.x & 63;                                              \
    int node = blockIdx.x * 4 + (threadIdx.x >> 6);                           \
    if (node >= n) return;                                                    \
    float di = dis[node];                                                     \
    int g = cnt[node], st = start[node];                                      \
    float acc = rs[node] * (float)T[node * NH + lane];                        \
    for (int base = 0; base < g; base += 64) {                                \
        int m = g - base; if (m > 64) m = 64;                                 \
        int sIdx = 0; float fv = 0.0f;                                        \
        if (lane < m) { sIdx = esrc[st + base + lane]; fv = rs[sIdx]; }       \
        int fvb = __float_as_int(fv);                                         \
        int j = 0;                                                            \
        for (; j + 7 < m; j += 8) {                                           \
            int s0 = __builtin_amdgcn_readlane(sIdx, j + 0);                  \
            int s1 = __builtin_amdgcn_readlane(sIdx, j + 1);                  \
            int s2 = __builtin_amdgcn_readlane(sIdx, j + 2);                  \
            int s3 = __builtin_amdgcn_readlane(sIdx, j + 3);                  \
            int s4 = __builtin_amdgcn_readlane(sIdx, j + 4);                  \
            int s5 = __builtin_amdgcn_readlane(sIdx, j + 5);                  \
            int s6 = __builtin_amdgcn_readlane(sIdx, j + 6);                  \
            int s7 = __builtin_amdgcn_readlane(sIdx, j + 7);                  \
            float f0 = __int_as_float(__builtin_amdgcn_readlane(fvb, j + 0)); \
            float f1 = __int_as_float(__builtin_amdgcn_readlane(fvb, j + 1)); \
            float f2 = __int_as_float(__builtin_amdgcn_readlane(fvb, j + 2)); \
            float f3 = __int_as_float(__builtin_amdgcn_readlane(fvb, j + 3)); \
            float f4 = __int_as_float(__builtin_amdgcn_readlane(fvb, j + 4)); \
            float f5 = __int_as_float(__builtin_amdgcn_readlane(fvb, j + 5)); \
            float f6 = __int_as_float(__builtin_amdgcn_readlane(fvb, j + 6)); \
            float f7 = __int_as_float(__builtin_amdgcn_readlane(fvb, j + 7)); \
            short v0 = (T + s0 * NH)[lane];                                   \
            short v1 = (T + s1 * NH)[lane];                                   \
            short v2 = (T + s2 * NH)[lane];                                   \
            short v3 = (T + s3 * NH)[lane];                                   \
            short v4 = (T + s4 * NH)[lane];                                   \
            short v5 = (T + s5 * NH)[lane];                                   \
            short v6 = (T + s6 * NH)[lane];                                   \
            short v7 = (T + s7 * NH)[lane];                                   \
            acc = fmaf(f0, (float)v0, acc);                                   \
            acc = fmaf(f1, (float)v1, acc);                                   \
            acc = fmaf(f2, (float)v2, acc);                                   \
            acc = fmaf(f3, (float)v3, acc);                                   \
            acc = fmaf(f4, (float)v4, acc);                                   \
            acc = fmaf(f5, (float)v5, acc);                                   \
            acc = fmaf(f6, (float)v6, acc);                                   \
            acc = fmaf(f7, (float)v7, acc);                                   \
        }                                                                     \
        for (; j < m; ++j) {                                                  \
            int s = __builtin_amdgcn_readlane(sIdx, j);                       \
            float f = __int_as_float(__builtin_amdgcn_readlane(fvb, j));      \
            acc = fmaf(f, (float)(T + s * NH)[lane], acc);                    \
        }                                                                     \
    }

// Layer-0: O[i] = di*acc + b (full 64-channel row out).
__global__ void __launch_bounds__(256) k_seg(
        const short* __restrict__ T, const float* __restrict__ rs,
        const int* __restrict__ esrc, const int* __restrict__ start,
        const int* __restrict__ cnt, const float* __restrict__ dis,
        const float* __restrict__ b, float* __restrict__ O, int n) {
    SEG_GATHER
    O[(long long)node * NH + lane] = di * acc + b[lane];
}

// Layer-1 + fused layer-2 transform: z1[c] = di*acc + b1[c] (c = lane);
// t = tanh(z1); t2[i] = di * (t @ W2) via 6-step full-wave butterfly.
__global__ void __launch_bounds__(256) k_seg1f(
        const short* __restrict__ T, const float* __restrict__ rs,
        const int* __restrict__ esrc, const int* __restrict__ start,
        const int* __restrict__ cnt, const float* __restrict__ dis,
        const float* __restrict__ b1, const float* __restrict__ W2,
        float2* __restrict__ t2, int n) {
    SEG_GATHER
    float t = tanhf(di * acc + b1[lane]);
    float2 w = ((const float2*)W2)[lane];   // W2[lane][0], W2[lane][1]
    float p0 = t * w.x;
    float p1 = t * w.y;
    #pragma unroll
    for (int msk = 32; msk; msk >>= 1) {
        p0 += __shfl_xor(p0, msk, 64);
        p1 += __shfl_xor(p1, msk, 64);
    }
    if (lane == 0) t2[node] = make_float2(di * p0, di * p1);
}

// Fused layer-2 aggregation + head: agg2 = di*(t2[i]+sum t2[s]) + b2;
// emb = tanh(agg2); out = emb @ Wc + bc.
__global__ void __launch_bounds__(256) k_seg2f(
        const float2* __restrict__ T2, const int* __restrict__ esrc,
        const int* __restrict__ start, const int* __restrict__ cnt,
        const float* __restrict__ dis, const float* __restrict__ b2,
        const float* __restrict__ Wc, const float* __restrict__ bc,
        float* __restrict__ out, float* __restrict__ emb, int n) {
    __shared__ float Wcs[32];
    __shared__ float bcs[16];
    if (threadIdx.x < 32) Wcs[threadIdx.x] = Wc[threadIdx.x];
    if (threadIdx.x < 16) bcs[threadIdx.x] = bc[threadIdx.x];
    __syncthreads();
    int i = blockIdx.x * 256 + threadIdx.x;
    if (i >= n) return;
    float di = dis[i];
    int g = cnt[i], st = start[i];
    float2 self = T2[i];
    float a0 = self.x, a1 = self.y;
    int j = 0;
    for (; j + 7 < g; j += 8) {
        int e0 = esrc[st+j],   e1 = esrc[st+j+1], e2 = esrc[st+j+2], e3 = esrc[st+j+3];
        int e4 = esrc[st+j+4], e5 = esrc[st+j+5], e6 = esrc[st+j+6], e7 = esrc[st+j+7];
        float2 v0 = T2[e0], v1 = T2[e1], v2 = T2[e2], v3 = T2[e3];
        float2 v4 = T2[e4], v5 = T2[e5], v6 = T2[e6], v7 = T2[e7];
        a0 += v0.x + v1.x + v2.x + v3.x + v4.x + v5.x + v6.x + v7.x;
        a1 += v0.y + v1.y + v2.y + v3.y + v4.y + v5.y + v6.y + v7.y;
    }
    for (; j < g; ++j) {
        float2 v = T2[esrc[st + j]];
        a0 += v.x; a1 += v.y;
    }
    float e0 = tanhf(a0 * di + b2[0]);
    float e1 = tanhf(a1 * di + b2[1]);
    *(float2*)&emb[(long long)i * 2] = make_float2(e0, e1);
    float* op = &out[(long long)i * 16];
    #pragma unroll
    for (int c4 = 0; c4 < 4; ++c4) {
        float4 o;
        o.x = e0 * Wcs[c4*4+0] + e1 * Wcs[16 + c4*4+0] + bcs[c4*4+0];
        o.y = e0 * Wcs[c4*4+1] + e1 * Wcs[16 + c4*4+1] + bcs[c4*4+1];
        o.z = e0 * Wcs[c4*4+2] + e1 * Wcs[16 + c4*4+2] + bcs[c4*4+2];
        o.w = e0 * Wcs[c4*4+3] + e1 * Wcs[16 + c4*4+3] + bcs[c4*4+3];
        *(float4*)&op[c4 * 4] = o;
    }
}

extern "C" void kernel_launch(void* const* d_in, const int* in_sizes, int n_in,
                              void* d_out, int out_size, void* d_ws, size_t ws_size,
                              hipStream_t stream) {
    const float* x  = (const float*)d_in[0];
    const int*   ei = (const int*)  d_in[1];
    const float* W0 = (const float*)d_in[2];
    const float* b0 = (const float*)d_in[3];
    const float* W1 = (const float*)d_in[4];
    const float* b1 = (const float*)d_in[5];
    const float* W2 = (const float*)d_in[6];
    const float* b2 = (const float*)d_in[7];
    const float* Wc = (const float*)d_in[8];
    const float* bc = (const float*)d_in[9];

    int N = in_sizes[0] / NF;
    int E = in_sizes[1] / 2;
    int NB = (N + NPB - 1) / NPB;   // 391 for N=100000 (must be <= MAXNB)

    float* out = (float*)d_out;                    // [N,16]
    float* emb = out + (long long)N * 16;          // [N,2]

    // workspace: T16[N*64 int16 = 12.8MB] | Bb[N*64 fp32] | dis[N] | rs[N] |
    //            cnt[N] | start[N] | esrc[E] | fmt
    // Preprocessing scratch (pairs/blockbase/ccnt/cstart ~ 8MB) overlays T16
    // (dead until the first k_gemm). t2 (0.8MB) lives at the start of Bb
    // (Bb dead after k_gemm<NH> consumes it; k_seg1f reads T16, writes t2).
    short* T16    = (short*)d_ws;
    float* Bb     = (float*)((char*)d_ws + (long long)N * NH * 2);
    float* dis    = Bb + (long long)N * NH;
    float* rs     = dis + N;
    int*   cnt    = (int*)(rs + N);
    int*   start  = cnt + N;
    int*   esrc   = start + N;
    int*   fmt    = esrc + E;
    float2* t2    = (float2*)Bb;

    int* pairs     = (int*)d_ws;                       // E ints (overlay T16)
    int* blockbase = pairs + E;                        // A1G * NB
    int* ccnt      = blockbase + (long long)A1G * NB;  // NB*16 (line-padded)
    int* cstart    = ccnt + NB * 16;                   // NB

    int nb_n  = (N + 255) / 256;
    int nb_g  = (N + 63) / 64;
    int nb_s  = (N + 3) / 4;
    int nb_i0 = (NB * 16 + 255) / 256;

    // per-call two-level bucket sort (inputs restored before every call)
    k_init0   <<<nb_i0, 256, 0, stream>>>(ei, fmt, ccnt, NB * 16);
    k_coarse  <<<A1G, 256, 0, stream>>>(ei, fmt, ccnt, blockbase, E, NB);
    k_cscan   <<<1, 512, 0, stream>>>(ccnt, cstart, NB);
    k_cscatter<<<A1G, 256, 0, stream>>>(ei, fmt, cstart, blockbase, pairs, E, NB);
    k_bucket  <<<NB, 256, 0, stream>>>(pairs, ccnt, cstart, esrc, cnt, start, dis, N);

    // layer 0 (no activation): fused gemm + rowwise int16 quant -> gather-sum
    k_gemm<NF><<<nb_g, 256, 0, stream>>>(x, W0, dis, T16, rs, N);
    k_seg     <<<nb_s, 256, 0, stream>>>(T16, rs, esrc, start, cnt, dis, b0, Bb, N);

    // layer 1 + fused layer-2 transform (tanh + @W2 in gather epilogue)
    k_gemm<NH><<<nb_g, 256, 0, stream>>>(Bb, W1, dis, T16, rs, N);
    k_seg1f   <<<nb_s, 256, 0, stream>>>(T16, rs, esrc, start, cnt, dis, b1, W2,
                                         t2, N);

    // layer-2 aggregation + head
    k_seg2f   <<<nb_n, 256, 0, stream>>>(t2, esrc, start, cnt, dis, b2, Wc, bc,
                                         out, emb, N);
}